// Round 1
// baseline (283.872 us; speedup 1.0000x reference)
//
#include <hip/hip_runtime.h>
#include <hip/hip_bf16.h>

typedef __bf16 bf16_t;
typedef __attribute__((ext_vector_type(8))) __bf16 bf16x8;
typedef __attribute__((ext_vector_type(4))) __bf16 bf16x4;
typedef __attribute__((ext_vector_type(4))) float f32x4;

static __device__ __forceinline__ f32x4 mfma16(bf16x8 a, bf16x8 b, f32x4 c) {
  return __builtin_amdgcn_mfma_f32_16x16x32_bf16(a, b, c, 0, 0, 0);
}

// async global->LDS, 16 B per lane. LDS dest is wave-uniform base + lane*16.
static __device__ __forceinline__ void async16(const void* g, void* l) {
  __builtin_amdgcn_global_load_lds(
      (const __attribute__((address_space(1))) void*)g,
      (__attribute__((address_space(3))) void*)l, 16, 0, 0);
}

static __device__ __forceinline__ bf16x8 load8f(const float* __restrict__ fp) {
  float4 a = *(const float4*)fp;
  float4 b = *(const float4*)(fp + 4);
  bf16x8 r;
  r[0] = (bf16_t)a.x; r[1] = (bf16_t)a.y; r[2] = (bf16_t)a.z; r[3] = (bf16_t)a.w;
  r[4] = (bf16_t)b.x; r[5] = (bf16_t)b.y; r[6] = (bf16_t)b.z; r[7] = (bf16_t)b.w;
  return r;
}

__global__ void invperm_kernel(const int* __restrict__ perm, int* __restrict__ invp, int S) {
  int i = blockIdx.x * 256 + threadIdx.x;
  if (i < S) invp[perm[i]] = i;
}

// x -> bf16, pre-applying the permutation: Xp[b*S+i] = (bf16) x[b*S+perm[i]]
__global__ __launch_bounds__(256) void convert_x_kernel(
    const float* __restrict__ x, bf16_t* __restrict__ Xp,
    const int* __restrict__ perm, int S, int H)
{
  int m = blockIdx.x * 4 + (threadIdx.x >> 6);
  int c = (threadIdx.x & 63) * 8;
  int b = m / S, i = m - b * S;
  long src = ((long)b * S + perm[i]) * H + c;
  *(bf16x8*)&Xp[(long)m * H + c] = load8f(x + src);
}

__global__ __launch_bounds__(256) void convert_w_kernel(
    const float* Wq, const float* bq, const float* Wk, const float* bk,
    const float* Wv, const float* bv, const float* Wo, const float* bo,
    bf16_t* __restrict__ Wb, bf16_t* __restrict__ bb, int H)
{
  const int z = blockIdx.z;
  const float* W  = (z == 0) ? Wq : (z == 1) ? Wk : (z == 2) ? Wv : Wo;
  const float* bi = (z == 0) ? bq : (z == 1) ? bk : (z == 2) ? bv : bo;
  bf16_t* dst = Wb + (long)z * H * H;
  int nwb = (H * H) / 2048;
  if ((int)blockIdx.x < nwb) {
    long e = (long)blockIdx.x * 2048 + threadIdx.x * 8;
    *(bf16x8*)&dst[e] = load8f(W + e);
  } else {
    int e = threadIdx.x * 8;
    if (e < H) *(bf16x8*)&bb[z * H + e] = load8f(bi + e);
  }
}

// ---------------------------------------------------------------------------
// Pipelined GEMM core: C = A * W^T + bias.
// BM=128 (A/tokens) x BN=256 (weights) x BK=64, 512 threads = 8 waves (2Mx4N),
// per-wave 64x64 output (4x4 f32x4 acc). 3-deep LDS ring (144 KB):
//   while computing tile t (buf t%3), stage tile t+2 into buf (t+2)%3, whose
//   previous occupant (tile t-1) was fully read BEFORE the barrier we just
//   crossed -> async landings can never race reads (structural WAR safety,
//   no latency assumptions). Main-loop gate is s_waitcnt vmcnt(6) (tile t+1's
//   6 in-flight loads), NEVER vmcnt(0) except the last tile -> loads stay in
//   flight across barriers (T3+T4). One s_barrier per K-tile, 256 MFMA between
//   barriers. setprio(1) around each 16-MFMA cluster (T5).
// Chunk-XOR swizzle (chunk' = chunk ^ (row&7)) as before: measured 0 bank
// conflicts.
// MODE 0: swapped-operand epilogue, packed bf16x4 column stores (Q/K)
// MODE 1: swapped-operand epilogue, packed float4 column stores (final out)
// MODE 2: original-operand epilogue, writes V^T as [b][head][chan][tok]
// GATHER: A row m is gathered from row b*S + invp[m%S] (inverse permutation)
// ---------------------------------------------------------------------------
template<int MODE, bool GATHER>
__device__ __forceinline__ void gemm_core(
    bf16_t (*__restrict__ At)[64],   // [3*128][64]
    bf16_t (*__restrict__ Bt)[64],   // [3*256][64]
    const bf16_t* __restrict__ A, const bf16_t* __restrict__ W,
    const bf16_t* __restrict__ bias, void* __restrict__ C,
    const int* __restrict__ invp, int N, int K, int S)
{
  const int bm = blockIdx.x * 128, bn = blockIdx.y * 256;
  const int tid = threadIdx.x, lane = tid & 63, w = tid >> 6;   // 8 waves
  const int qd = lane >> 4, ln = lane & 15, l7 = ln & 7;

  const int srow = lane >> 3;                   // 0..7 (row&7 of staged row)
  const int scol = ((lane & 7) ^ srow) * 8;     // swizzled global fetch chunk

  long asrc[2], wsrc[4];
  for (int u = 0; u < 2; ++u) {
    int mg = bm + 16 * w + 8 * u + srow;
    if (GATHER) { int b_ = mg / S; asrc[u] = ((long)b_ * S + invp[mg - b_ * S]) * K + scol; }
    else        { asrc[u] = (long)mg * K + scol; }
  }
  for (int u = 0; u < 4; ++u)
    wsrc[u] = (long)(bn + 32 * w + 8 * u + srow) * K + scol;

  f32x4 acc[4][4];
  for (int i = 0; i < 4; ++i)
    for (int j = 0; j < 4; ++j)
      acc[i][j] = (f32x4){0.f, 0.f, 0.f, 0.f};

  const int wmo = (w & 1) * 64;        // wave row offset within BM=128
  const int wno = (w >> 1) * 64;       // wave col offset within BN=256
  const int NT = K >> 6;               // 8 K-tiles for K=512

  // prologue: stage tiles 0 and 1 (6 loads/thread each)
  for (int t = 0; t < 2; ++t) {
    const int k0 = t << 6;
    for (int u = 0; u < 2; ++u)
      async16(&A[asrc[u] + k0], &At[t * 128 + 16 * w + 8 * u][0]);
    for (int u = 0; u < 4; ++u)
      async16(&W[wsrc[u] + k0], &Bt[t * 256 + 32 * w + 8 * u][0]);
  }

  int s = 0;
  for (int t = 0; t < NT; ++t) {
    // gate: everything except tile t+1's 6 loads must have landed
    if (t + 1 < NT) asm volatile("s_waitcnt vmcnt(6)" ::: "memory");
    else            asm volatile("s_waitcnt vmcnt(0)" ::: "memory");
    __builtin_amdgcn_s_barrier();
    asm volatile("" ::: "memory");     // keep ds_reads/stages below the barrier

    const bf16_t (*Ab)[64] = At + s * 128;
    const bf16_t (*Bb)[64] = Bt + s * 256;
    int s2 = s + 2; if (s2 >= 3) s2 -= 3;        // ring slot for tile t+2
    const int k2 = (t + 2) << 6;
    const bool st = (t + 2 < NT);

    // ---- phase 0 (k-slice 0) ----
    {
      const int ce = (qd ^ l7) * 8;
      bf16x8 af[4], bfr[4];
      for (int i = 0; i < 4; ++i)
        af[i] = *(const bf16x8*)&Ab[wmo + 16 * i + ln][ce];
      for (int j = 0; j < 4; ++j)
        bfr[j] = *(const bf16x8*)&Bb[wno + 16 * j + ln][ce];
      if (st) {
        async16(&A[asrc[0] + k2], &At[s2 * 128 + 16 * w][0]);
        async16(&W[wsrc[0] + k2], &Bt[s2 * 256 + 32 * w][0]);
        async16(&W[wsrc[1] + k2], &Bt[s2 * 256 + 32 * w + 8][0]);
      }
      __builtin_amdgcn_s_setprio(1);
      for (int i = 0; i < 4; ++i)
        for (int j = 0; j < 4; ++j) {
          if (MODE == 2) acc[i][j] = mfma16(af[i], bfr[j], acc[i][j]);
          else           acc[i][j] = mfma16(bfr[j], af[i], acc[i][j]);
        }
      __builtin_amdgcn_s_setprio(0);
    }
    // ---- phase 1 (k-slice 1) ----
    {
      const int ce = ((4 + qd) ^ l7) * 8;
      bf16x8 af[4], bfr[4];
      for (int i = 0; i < 4; ++i)
        af[i] = *(const bf16x8*)&Ab[wmo + 16 * i + ln][ce];
      for (int j = 0; j < 4; ++j)
        bfr[j] = *(const bf16x8*)&Bb[wno + 16 * j + ln][ce];
      if (st) {
        async16(&A[asrc[1] + k2], &At[s2 * 128 + 16 * w + 8][0]);
        async16(&W[wsrc[2] + k2], &Bt[s2 * 256 + 32 * w + 16][0]);
        async16(&W[wsrc[3] + k2], &Bt[s2 * 256 + 32 * w + 24][0]);
      }
      __builtin_amdgcn_s_setprio(1);
      for (int i = 0; i < 4; ++i)
        for (int j = 0; j < 4; ++j) {
          if (MODE == 2) acc[i][j] = mfma16(af[i], bfr[j], acc[i][j]);
          else           acc[i][j] = mfma16(bfr[j], af[i], acc[i][j]);
        }
      __builtin_amdgcn_s_setprio(0);
    }
    ++s; if (s == 3) s = 0;
  }

  if (MODE == 2) {
    // lane holds C[m = bm+wmo+16i+4qd+r][n = bn+wno+16j+ln]; write V^T packed
    // along tokens: Vt[(b*heads+h)*N + n][tok], tok = 4 consecutive.
    const int heads = S >> 6;
    const int b_ = bm / S;
    const int ip0 = bm - b_ * S;
    for (int j = 0; j < 4; ++j) {
      int n = bn + wno + 16 * j + ln;
      float bv = (float)bias[n];
      for (int i = 0; i < 4; ++i) {
        int il = ip0 + wmo + 16 * i + 4 * qd;
        int h = il >> 6, tok = il & 63;
        bf16x4 pk;
        for (int r = 0; r < 4; ++r) pk[r] = (bf16_t)(acc[i][j][r] + bv);
        *(bf16x4*)&((bf16_t*)C)[(((long)(b_ * heads + h) * N + n) << 6) + tok] = pk;
      }
    }
  } else {
    // swapped: lane holds C[m = bm+wmo+16i+ln][n = bn+wno+16j+4qd + r]
    for (int j = 0; j < 4; ++j) {
      int nb = bn + wno + 16 * j + 4 * qd;
      bf16x4 b4 = *(const bf16x4*)&bias[nb];
      for (int i = 0; i < 4; ++i) {
        int m = bm + wmo + 16 * i + ln;
        if (MODE == 1) {
          float4 pk = {acc[i][j][0] + (float)b4[0], acc[i][j][1] + (float)b4[1],
                       acc[i][j][2] + (float)b4[2], acc[i][j][3] + (float)b4[3]};
          *(float4*)&((float*)C)[(long)m * N + nb] = pk;
        } else {
          bf16x4 pk;
          for (int r = 0; r < 4; ++r) pk[r] = (bf16_t)(acc[i][j][r] + (float)b4[r]);
          *(bf16x4*)&((bf16_t*)C)[(long)m * N + nb] = pk;
        }
      }
    }
  }
}

__global__ __launch_bounds__(512, 2) void gemm_qkv_kernel(
    const bf16_t* __restrict__ Xp, const bf16_t* __restrict__ Wb,
    const bf16_t* __restrict__ bb,
    bf16_t* __restrict__ Qp, bf16_t* __restrict__ Kp, bf16_t* __restrict__ Vt,
    int S, int H)
{
  __shared__ bf16_t At[3 * 128][64];   // 48 KB  (A ring, 3 tiles)
  __shared__ bf16_t Bt[3 * 256][64];   // 96 KB  (B ring, 3 tiles)
  const int z = blockIdx.z;
  if (z == 0)      gemm_core<0, false>(At, Bt, Xp, Wb,             bb,       Qp, nullptr, H, H, S);
  else if (z == 1) gemm_core<0, false>(At, Bt, Xp, Wb + (long)H*H, bb + H,   Kp, nullptr, H, H, S);
  else             gemm_core<2, false>(At, Bt, Xp, Wb + 2L*H*H,    bb + 2*H, Vt, nullptr, H, H, S);
}

__global__ __launch_bounds__(512, 2) void gemm_o_kernel(
    const bf16_t* __restrict__ Att, const bf16_t* __restrict__ Wb,
    const bf16_t* __restrict__ bb, float* __restrict__ C,
    const int* __restrict__ invp, int S, int H)
{
  __shared__ bf16_t At[3 * 128][64];
  __shared__ bf16_t Bt[3 * 256][64];
  gemm_core<1, true>(At, Bt, Att, Wb + 3L * H * H, bb + 3 * H, C, invp, H, H, S);
}

// One block per (b, head). K and V^T slabs in SEPARATE LDS regions: V asyncs
// are issued right after the K barrier so their latency overlaps the QK MFMA
// phase; the pre-PV barrier drains V cheaply. 137 KB LDS -> 1 block/CU.
__global__ __launch_bounds__(256) void attn_kernel(
    const bf16_t* __restrict__ Qp, const bf16_t* __restrict__ Kp,
    const bf16_t* __restrict__ Vt, bf16_t* __restrict__ Att,
    int S, int H)
{
  const int heads = S >> 6;
  const int b = blockIdx.x / heads;
  const int h = blockIdx.x % heads;
  const long qkbase = ((long)b * S + h * 64) * H;
  const long vbase  = (long)(b * heads + h) * H * 64;

  const int tid = threadIdx.x, lane = tid & 63, w = tid >> 6;
  const int qd = lane >> 4, ln = lane & 15;
  const int l7 = ln & 7;

  __shared__ bf16_t Ks[64 * 512];   // 64 KB K slab
  __shared__ bf16_t Vs[512 * 64];   // 64 KB V^T slab (separate: enables overlap)
  __shared__ bf16_t P[64][72];      // softmax weights

  // stage K: one full row (512 bf16) per instr, low-3 chunk swizzle
  for (int r0 = 0; r0 < 16; ++r0) {
    int row = 16 * w + r0;
    async16(&Kp[qkbase + (long)row * H + (lane ^ (row & 7)) * 8], &Ks[row * 512]);
  }
  bf16x8 qf[16];
  for (int t = 0; t < 16; ++t)
    qf[t] = *(const bf16x8*)&Qp[qkbase + (long)(16 * w + ln) * H + t * 32 + qd * 8];
  __syncthreads();            // drains K (and Q frags)

  // issue V^T staging NOW; it completes during the QK/softmax phase
  for (int u = 0; u < 16; ++u) {
    int rowb = 128 * w + 8 * u;
    async16(&Vt[vbase + (long)(rowb + (lane >> 3)) * 64 +
                (((lane & 7) ^ ((lane >> 3) & 7)) * 8)],
            &Vs[rowb * 64]);
  }

  // scores = Q K^T; lane (w,qd,ln) gets S[16w+4qd+r][16j+ln]
  f32x4 accs[4];
  for (int j = 0; j < 4; ++j) accs[j] = (f32x4){0.f, 0.f, 0.f, 0.f};
  for (int t = 0; t < 16; ++t)
    for (int j = 0; j < 4; ++j) {
      bf16x8 kf = *(const bf16x8*)&Ks[(16 * j + ln) * 512 + (((t * 4 + qd) ^ l7) * 8)];
      accs[j] = mfma16(qf[t], kf, accs[j]);
    }

  // register softmax, normalized weights into P (LDS)
  const float rscale = rsqrtf((float)H);
  for (int r = 0; r < 4; ++r) {
    float s[4];
    for (int j = 0; j < 4; ++j) s[j] = accs[j][r] * rscale;
    float mx = fmaxf(fmaxf(s[0], s[1]), fmaxf(s[2], s[3]));
    mx = fmaxf(mx, __shfl_xor(mx, 1));
    mx = fmaxf(mx, __shfl_xor(mx, 2));
    mx = fmaxf(mx, __shfl_xor(mx, 4));
    mx = fmaxf(mx, __shfl_xor(mx, 8));
    float e[4], sum = 0.f;
    for (int j = 0; j < 4; ++j) {
      e[j] = (float)(bf16_t)__expf(s[j] - mx);
      sum += e[j];
    }
    sum += __shfl_xor(sum, 1);
    sum += __shfl_xor(sum, 2);
    sum += __shfl_xor(sum, 4);
    sum += __shfl_xor(sum, 8);
    float rs = 1.f / sum;
    for (int j = 0; j < 4; ++j)
      P[16 * w + qd * 4 + r][16 * j + ln] = (bf16_t)(e[j] * rs);
  }
  __syncthreads();   // drains V (mostly landed) + makes P visible

  // attended = P V via swapped operands: lane holds D[m=16w+ln][nb + r]
  const int m = 16 * w + ln;
  const long obase = ((long)b * S + h * 64 + m) * H;
  for (int nc = 0; nc < 4; ++nc) {
    f32x4 acco[8];
    for (int j = 0; j < 8; ++j) acco[j] = (f32x4){0.f, 0.f, 0.f, 0.f};
    for (int ks = 0; ks < 2; ++ks) {
      bf16x8 pf = *(const bf16x8*)&P[m][ks * 32 + qd * 8];
      for (int j = 0; j < 8; ++j) {
        int row = nc * 128 + 16 * j + ln;
        bf16x8 vf = *(const bf16x8*)&Vs[row * 64 + (((ks * 4 + qd) ^ l7) * 8)];
        acco[j] = mfma16(vf, pf, acco[j]);
      }
    }
    for (int j = 0; j < 8; ++j) {
      int nb = nc * 128 + 16 * j + 4 * qd;
      bf16x4 pk;
      for (int r = 0; r < 4; ++r) pk[r] = (bf16_t)acco[j][r];
      *(bf16x4*)&Att[obase + nb] = pk;
    }
  }
}

extern "C" void kernel_launch(void* const* d_in, const int* in_sizes, int n_in,
                              void* d_out, int out_size, void* d_ws, size_t ws_size,
                              hipStream_t stream)
{
  const float* x  = (const float*)d_in[0];
  const float* Wq = (const float*)d_in[1]; const float* bq = (const float*)d_in[2];
  const float* Wk = (const float*)d_in[3]; const float* bk = (const float*)d_in[4];
  const float* Wv = (const float*)d_in[5]; const float* bv = (const float*)d_in[6];
  const float* Wo = (const float*)d_in[7]; const float* bo = (const float*)d_in[8];
  const int* perm = (const int*)d_in[9];

  const int S = in_sizes[9];                 // 4096
  const int H = in_sizes[2];                 // 512
  const int B = in_sizes[0] / (S * H);       // 8
  const int M = B * S;                       // 32768

  size_t bufB = (size_t)M * H * sizeof(bf16_t);          // 32 MB
  size_t wB   = 4 * (size_t)H * H * sizeof(bf16_t);
  size_t need = 256 + 4 * bufB + wB + 4 * H * 2 + (size_t)S * 4;
  if (ws_size < need) return;

  char* p = (char*)d_ws;  p += 256;
  bf16_t* Xp = (bf16_t*)p;  p += bufB;        // aliased as Att after QKV GEMM
  bf16_t* Qp = (bf16_t*)p;  p += bufB;
  bf16_t* Kp = (bf16_t*)p;  p += bufB;
  bf16_t* Vt = (bf16_t*)p;  p += bufB;        // V^T: [b][head][chan][tok]
  bf16_t* Wb = (bf16_t*)p;  p += wB;
  bf16_t* bb = (bf16_t*)p;  p += 4 * H * 2;
  int* invp  = (int*)p;
  bf16_t* Att = Xp;

  invperm_kernel<<<(S + 255) / 256, 256, 0, stream>>>(perm, invp, S);
  convert_x_kernel<<<(M * H) / 2048, 256, 0, stream>>>(x, Xp, perm, S, H);
  dim3 gw((H * H) / 2048 + 1, 1, 4);
  convert_w_kernel<<<gw, 256, 0, stream>>>(Wq, bq, Wk, bk, Wv, bv, Wo, bo,
                                           Wb, bb, H);

  dim3 g1(M / 128, H / 256, 3);
  gemm_qkv_kernel<<<g1, 512, 0, stream>>>(Xp, Wb, bb, Qp, Kp, Vt, S, H);

  dim3 g2(B * (S / 64));
  attn_kernel<<<g2, 256, 0, stream>>>(Qp, Kp, Vt, Att, S, H);

  dim3 g3(M / 128, H / 256, 1);
  gemm_o_kernel<<<g3, 512, 0, stream>>>(Att, Wb, bb, (float*)d_out, invp, S, H);
}

// Round 3
// 267.233 us; speedup vs baseline: 1.0623x; 1.0623x over previous
//
#include <hip/hip_runtime.h>
#include <hip/hip_bf16.h>

typedef __bf16 bf16_t;
typedef __attribute__((ext_vector_type(8))) __bf16 bf16x8;
typedef __attribute__((ext_vector_type(4))) __bf16 bf16x4;
typedef __attribute__((ext_vector_type(4))) float f32x4;

static __device__ __forceinline__ f32x4 mfma16(bf16x8 a, bf16x8 b, f32x4 c) {
  return __builtin_amdgcn_mfma_f32_16x16x32_bf16(a, b, c, 0, 0, 0);
}

// async global->LDS, 16 B per lane. LDS dest is wave-uniform base + lane*16.
static __device__ __forceinline__ void async16(const void* g, void* l) {
  __builtin_amdgcn_global_load_lds(
      (const __attribute__((address_space(1))) void*)g,
      (__attribute__((address_space(3))) void*)l, 16, 0, 0);
}

static __device__ __forceinline__ bf16x8 load8f(const float* __restrict__ fp) {
  float4 a = *(const float4*)fp;
  float4 b = *(const float4*)(fp + 4);
  bf16x8 r;
  r[0] = (bf16_t)a.x; r[1] = (bf16_t)a.y; r[2] = (bf16_t)a.z; r[3] = (bf16_t)a.w;
  r[4] = (bf16_t)b.x; r[5] = (bf16_t)b.y; r[6] = (bf16_t)b.z; r[7] = (bf16_t)b.w;
  return r;
}

__global__ void invperm_kernel(const int* __restrict__ perm, int* __restrict__ invp, int S) {
  int i = blockIdx.x * 256 + threadIdx.x;
  if (i < S) invp[perm[i]] = i;
}

// x -> bf16, pre-applying the permutation: Xp[b*S+i] = (bf16) x[b*S+perm[i]]
__global__ __launch_bounds__(256) void convert_x_kernel(
    const float* __restrict__ x, bf16_t* __restrict__ Xp,
    const int* __restrict__ perm, int S, int H)
{
  int m = blockIdx.x * 4 + (threadIdx.x >> 6);
  int c = (threadIdx.x & 63) * 8;
  int b = m / S, i = m - b * S;
  long src = ((long)b * S + perm[i]) * H + c;
  *(bf16x8*)&Xp[(long)m * H + c] = load8f(x + src);
}

__global__ __launch_bounds__(256) void convert_w_kernel(
    const float* Wq, const float* bq, const float* Wk, const float* bk,
    const float* Wv, const float* bv, const float* Wo, const float* bo,
    bf16_t* __restrict__ Wb, bf16_t* __restrict__ bb, int H)
{
  const int z = blockIdx.z;
  const float* W  = (z == 0) ? Wq : (z == 1) ? Wk : (z == 2) ? Wv : Wo;
  const float* bi = (z == 0) ? bq : (z == 1) ? bk : (z == 2) ? bv : bo;
  bf16_t* dst = Wb + (long)z * H * H;
  int nwb = (H * H) / 2048;
  if ((int)blockIdx.x < nwb) {
    long e = (long)blockIdx.x * 2048 + threadIdx.x * 8;
    *(bf16x8*)&dst[e] = load8f(W + e);
  } else {
    int e = threadIdx.x * 8;
    if (e < H) *(bf16x8*)&bb[z * H + e] = load8f(bi + e);
  }
}

// ---------------------------------------------------------------------------
// 8-phase-template GEMM core (m201 port): C = A * W^T + bias.
// BM=BN=256, BK=64, 512 threads = 8 waves (2M x 4N), per-wave 128x64 output
// (acc[2][2][4][2] f32x4 = 128 VGPR). LDS = 2 slots x (A 32KB + B 32KB) =
// 128 KB. Per K-tile: 4 phases, phase (rh,ch) order (0,0),(0,1),(1,1),(1,0)
// so A-frags persist across 2 phases and B-frags across 2 phases.
// Each phase: {ds_read frags || stage 1 half-tile (2x global_load_lds)} ->
// s_barrier -> lgkmcnt(0) -> setprio(1) 16x MFMA setprio(0) -> s_barrier.
// Staging order per tile kt (targets slot kt+1): A-half0 @p1, B-ch0 @p2,
// B-ch1 @p3, A-half1 @p4 (consumed 3-4 phases later).
// Gate: s_waitcnt vmcnt(2) at TOP of every phase (counted, never 0 in steady
// state). Safety (derived, not latency-based): the half consumed at phase t
// was staged at t-3 by each wave; that wave's gate at t-1 (vmcnt(2)) forced
// its <=t-3 stages landed BEFORE the end-of-(t-1) barrier that precedes the
// reads -> cross-wave RAW safe. Last tile: vmcnt(0) once at p2. WAR:
// staging targets the slot whose last readers finished >=4 barriers ago.
// Chunk-XOR swizzle (chunk' = chunk ^ (row&7)): staged via pre-swizzled
// per-lane global source (linear LDS dest); read-side XOR cancels because
// fragment row&7 == ln&7. Measured 0 bank conflicts with this scheme.
// MODE 0: swapped-operand epilogue, packed bf16x4 column stores (Q/K)
// MODE 1: swapped-operand epilogue, packed float4 column stores (final out)
// MODE 2: original-operand epilogue, writes V^T as [b][head][chan][tok]
// GATHER: A row m is gathered from row b*S + invp[m%S] (inverse permutation)
// ---------------------------------------------------------------------------
template<int MODE, bool GATHER>
__device__ __forceinline__ void gemm_core(
    bf16_t (*__restrict__ At)[64],   // [2*256][64]
    bf16_t (*__restrict__ Bt)[64],   // [2*256][64]
    const bf16_t* __restrict__ A, const bf16_t* __restrict__ W,
    const bf16_t* __restrict__ bias, void* __restrict__ C,
    const int* __restrict__ invp, int N, int K, int S)
{
  const int bm = blockIdx.x * 256, bn = blockIdx.y * 256;
  const int tid = threadIdx.x, lane = tid & 63, w = tid >> 6;   // 8 waves
  const int qd = lane >> 4, ln = lane & 15, l7 = ln & 7;
  const int wm = w & 1, wn = w >> 1;            // 2M x 4N wave grid
  const int srow = lane >> 3;                   // 0..7 (row&7 of staged row)
  const int scol = ((lane & 7) ^ srow) * 8;     // swizzled global fetch chunk

  // Stage-group tables. A-half h covers the rh=h 64-row slices of both wave
  // halves: h=0 -> rows 0-63 & 128-191 (groups 0-7,16-23); h=1 -> +8 groups.
  // B-half c covers the ch=c 32-row slices of all 4 wn quarters.
  int ga[2][2], gb[2][2];
#pragma unroll
  for (int u = 0; u < 2; ++u) {
    int ix = w + 8 * u;                         // 0..15
    ga[0][u] = (ix & 7) + ((ix >> 3) << 4);
    ga[1][u] = ga[0][u] + 8;
    gb[0][u] = (ix & 3) + ((ix >> 2) << 3);
    gb[1][u] = gb[0][u] + 4;
  }
  long aoff[2][2], woff[2][2];
#pragma unroll
  for (int h = 0; h < 2; ++h)
#pragma unroll
    for (int u = 0; u < 2; ++u) {
      int mg = bm + ga[h][u] * 8 + srow;
      if (GATHER) { int b_ = mg / S; aoff[h][u] = ((long)b_ * S + invp[mg - b_ * S]) * K + scol; }
      else        { aoff[h][u] = (long)mg * K + scol; }
      woff[h][u] = (long)(bn + gb[h][u] * 8 + srow) * K + scol;
    }

  f32x4 acc[2][2][4][2];
#pragma unroll
  for (int a = 0; a < 2; ++a)
#pragma unroll
    for (int b = 0; b < 2; ++b)
#pragma unroll
      for (int i = 0; i < 4; ++i)
#pragma unroll
        for (int j = 0; j < 2; ++j)
          acc[a][b][i][j] = (f32x4){0.f, 0.f, 0.f, 0.f};

  bf16x8 af[4][2], bfr[2][2];
  const int NT = K >> 6;                         // 8 K-tiles for K=512

#define LOAD_A(RH)                                                            \
  _Pragma("unroll") for (int i = 0; i < 4; ++i)                               \
  _Pragma("unroll") for (int ks = 0; ks < 2; ++ks)                            \
    af[i][ks] = *(const bf16x8*)&At[sb + wm * 128 + (RH) * 64 + 16 * i + ln]  \
                                   [((ks * 4 + qd) ^ l7) * 8];
#define LOAD_B(CH)                                                            \
  _Pragma("unroll") for (int j = 0; j < 2; ++j)                               \
  _Pragma("unroll") for (int ks = 0; ks < 2; ++ks)                            \
    bfr[j][ks] = *(const bf16x8*)&Bt[sb + wn * 64 + (CH) * 32 + 16 * j + ln]  \
                                    [((ks * 4 + qd) ^ l7) * 8];
#define STAGE_A(HH)                                                           \
  if (st) {                                                                   \
    async16(&A[aoff[HH][0] + k2], &At[so + ga[HH][0] * 8][0]);                \
    async16(&A[aoff[HH][1] + k2], &At[so + ga[HH][1] * 8][0]);                \
  }
#define STAGE_B(CH)                                                           \
  if (st) {                                                                   \
    async16(&W[woff[CH][0] + k2], &Bt[so + gb[CH][0] * 8][0]);                \
    async16(&W[woff[CH][1] + k2], &Bt[so + gb[CH][1] * 8][0]);                \
  }
#define MFMA_Q(RH, CH)                                                        \
  __builtin_amdgcn_s_setprio(1);                                              \
  _Pragma("unroll") for (int i = 0; i < 4; ++i)                               \
  _Pragma("unroll") for (int j = 0; j < 2; ++j)                               \
  _Pragma("unroll") for (int ks = 0; ks < 2; ++ks) {                          \
    if (MODE == 2) acc[RH][CH][i][j] = mfma16(af[i][ks], bfr[j][ks], acc[RH][CH][i][j]); \
    else           acc[RH][CH][i][j] = mfma16(bfr[j][ks], af[i][ks], acc[RH][CH][i][j]); \
  }                                                                           \
  __builtin_amdgcn_s_setprio(0);
#define GATE2 asm volatile("s_waitcnt vmcnt(2)" ::: "memory")
#define GATE0 asm volatile("s_waitcnt vmcnt(0)" ::: "memory")
#define PH_MID                                                                \
  __builtin_amdgcn_s_barrier();                                               \
  asm volatile("s_waitcnt lgkmcnt(0)" ::: "memory");
#define PH_END __builtin_amdgcn_s_barrier();

  // prologue: stage tile 0 into slot 0 in deadline order A0,B0,B1,A1
  async16(&A[aoff[0][0]], &At[ga[0][0] * 8][0]);
  async16(&A[aoff[0][1]], &At[ga[0][1] * 8][0]);
  async16(&W[woff[0][0]], &Bt[gb[0][0] * 8][0]);
  async16(&W[woff[0][1]], &Bt[gb[0][1] * 8][0]);
  async16(&W[woff[1][0]], &Bt[gb[1][0] * 8][0]);
  async16(&W[woff[1][1]], &Bt[gb[1][1] * 8][0]);
  async16(&A[aoff[1][0]], &At[ga[1][0] * 8][0]);
  async16(&A[aoff[1][1]], &At[ga[1][1] * 8][0]);
  GATE2;                       // A0,B0,B1 landed (all but newest 2) pre-barrier
  __builtin_amdgcn_s_barrier();

  for (int kt = 0; kt < NT; ++kt) {
    const int sb = (kt & 1) << 8;          // compute-slot row base
    const int so = ((kt + 1) & 1) << 8;    // stage-slot row base
    const long k2 = (long)(kt + 1) << 6;
    const bool st = (kt + 1 < NT);

    // ---- phase 1: (rh=0, ch=0) ----
    GATE2;
    LOAD_A(0)
    LOAD_B(0)
    STAGE_A(0)
    PH_MID
    MFMA_Q(0, 0)
    PH_END
    // ---- phase 2: (rh=0, ch=1) ----
    if (st) { GATE2; } else { GATE0; }     // last tile: drain once here
    LOAD_B(1)
    STAGE_B(0)
    PH_MID
    MFMA_Q(0, 1)
    PH_END
    // ---- phase 3: (rh=1, ch=1) ----
    if (st) { GATE2; }
    LOAD_A(1)
    STAGE_B(1)
    PH_MID
    MFMA_Q(1, 1)
    PH_END
    // ---- phase 4: (rh=1, ch=0) ----
    if (st) { GATE2; }
    LOAD_B(0)
    STAGE_A(1)
    PH_MID
    MFMA_Q(1, 0)
    PH_END
  }

#undef LOAD_A
#undef LOAD_B
#undef STAGE_A
#undef STAGE_B
#undef MFMA_Q
#undef GATE2
#undef GATE0
#undef PH_MID
#undef PH_END

  if (MODE == 2) {
    // lane holds C[m = bm+wm*128+rh*64+16i+4qd+r][n = bn+wn*64+ch*32+16j+ln];
    // write V^T packed along tokens: Vt[(b*heads+h)*N + n][tok].
    const int heads = S >> 6;
    const int b_ = bm / S;
    const int ip0 = bm - b_ * S;
#pragma unroll
    for (int rh = 0; rh < 2; ++rh)
#pragma unroll
      for (int ch = 0; ch < 2; ++ch)
#pragma unroll
        for (int j = 0; j < 2; ++j) {
          int n = bn + wn * 64 + ch * 32 + 16 * j + ln;
          float bv = (float)bias[n];
#pragma unroll
          for (int i = 0; i < 4; ++i) {
            int il = ip0 + wm * 128 + rh * 64 + 16 * i + 4 * qd;
            int h = il >> 6, tok = il & 63;
            bf16x4 pk;
#pragma unroll
            for (int r = 0; r < 4; ++r) pk[r] = (bf16_t)(acc[rh][ch][i][j][r] + bv);
            *(bf16x4*)&((bf16_t*)C)[(((long)(b_ * heads + h) * N + n) << 6) + tok] = pk;
          }
        }
  } else {
    // swapped: lane holds C[m = bm+wm*128+rh*64+16i+ln][n = bn+wn*64+ch*32+16j+4qd+r]
#pragma unroll
    for (int rh = 0; rh < 2; ++rh)
#pragma unroll
      for (int ch = 0; ch < 2; ++ch)
#pragma unroll
        for (int j = 0; j < 2; ++j) {
          int nb = bn + wn * 64 + ch * 32 + 16 * j + 4 * qd;
          bf16x4 b4 = *(const bf16x4*)&bias[nb];
#pragma unroll
          for (int i = 0; i < 4; ++i) {
            int m = bm + wm * 128 + rh * 64 + 16 * i + ln;
            if (MODE == 1) {
              float4 pk = {acc[rh][ch][i][j][0] + (float)b4[0], acc[rh][ch][i][j][1] + (float)b4[1],
                           acc[rh][ch][i][j][2] + (float)b4[2], acc[rh][ch][i][j][3] + (float)b4[3]};
              *(float4*)&((float*)C)[(long)m * N + nb] = pk;
            } else {
              bf16x4 pk;
#pragma unroll
              for (int r = 0; r < 4; ++r) pk[r] = (bf16_t)(acc[rh][ch][i][j][r] + (float)b4[r]);
              *(bf16x4*)&((bf16_t*)C)[(long)m * N + nb] = pk;
            }
          }
        }
  }
}

__global__ __launch_bounds__(512, 2) void gemm_qkv_kernel(
    const bf16_t* __restrict__ Xp, const bf16_t* __restrict__ Wb,
    const bf16_t* __restrict__ bb,
    bf16_t* __restrict__ Qp, bf16_t* __restrict__ Kp, bf16_t* __restrict__ Vt,
    int S, int H)
{
  __shared__ bf16_t At[512][64];   // 64 KB (2 slots x 256 rows)
  __shared__ bf16_t Bt[512][64];   // 64 KB
  const int z = blockIdx.z;
  if (z < 2)
    gemm_core<0, false>(At, Bt, Xp, Wb + (long)z * H * H, bb + z * H,
                        z ? (void*)Kp : (void*)Qp, nullptr, H, H, S);
  else
    gemm_core<2, false>(At, Bt, Xp, Wb + 2L * H * H, bb + 2 * H, Vt, nullptr, H, H, S);
}

__global__ __launch_bounds__(512, 2) void gemm_o_kernel(
    const bf16_t* __restrict__ Att, const bf16_t* __restrict__ Wb,
    const bf16_t* __restrict__ bb, float* __restrict__ C,
    const int* __restrict__ invp, int S, int H)
{
  __shared__ bf16_t At[512][64];
  __shared__ bf16_t Bt[512][64];
  gemm_core<1, true>(At, Bt, Att, Wb + 3L * H * H, bb + 3 * H, C, invp, H, H, S);
}

// One block per (b, head). K and V^T slabs in SEPARATE LDS regions: V asyncs
// are issued right after the K barrier so their latency overlaps the QK MFMA
// phase; the pre-PV barrier drains V cheaply. 137 KB LDS -> 1 block/CU.
__global__ __launch_bounds__(256) void attn_kernel(
    const bf16_t* __restrict__ Qp, const bf16_t* __restrict__ Kp,
    const bf16_t* __restrict__ Vt, bf16_t* __restrict__ Att,
    int S, int H)
{
  const int heads = S >> 6;
  const int b = blockIdx.x / heads;
  const int h = blockIdx.x % heads;
  const long qkbase = ((long)b * S + h * 64) * H;
  const long vbase  = (long)(b * heads + h) * H * 64;

  const int tid = threadIdx.x, lane = tid & 63, w = tid >> 6;
  const int qd = lane >> 4, ln = lane & 15;
  const int l7 = ln & 7;

  __shared__ bf16_t Ks[64 * 512];   // 64 KB K slab
  __shared__ bf16_t Vs[512 * 64];   // 64 KB V^T slab (separate: enables overlap)
  __shared__ bf16_t P[64][72];      // softmax weights

  // stage K: one full row (512 bf16) per instr, low-3 chunk swizzle
  for (int r0 = 0; r0 < 16; ++r0) {
    int row = 16 * w + r0;
    async16(&Kp[qkbase + (long)row * H + (lane ^ (row & 7)) * 8], &Ks[row * 512]);
  }
  bf16x8 qf[16];
  for (int t = 0; t < 16; ++t)
    qf[t] = *(const bf16x8*)&Qp[qkbase + (long)(16 * w + ln) * H + t * 32 + qd * 8];
  __syncthreads();            // drains K (and Q frags)

  // issue V^T staging NOW; it completes during the QK/softmax phase
  for (int u = 0; u < 16; ++u) {
    int rowb = 128 * w + 8 * u;
    async16(&Vt[vbase + (long)(rowb + (lane >> 3)) * 64 +
                (((lane & 7) ^ ((lane >> 3) & 7)) * 8)],
            &Vs[rowb * 64]);
  }

  // scores = Q K^T; lane (w,qd,ln) gets S[16w+4qd+r][16j+ln]
  f32x4 accs[4];
  for (int j = 0; j < 4; ++j) accs[j] = (f32x4){0.f, 0.f, 0.f, 0.f};
  for (int t = 0; t < 16; ++t)
    for (int j = 0; j < 4; ++j) {
      bf16x8 kf = *(const bf16x8*)&Ks[(16 * j + ln) * 512 + (((t * 4 + qd) ^ l7) * 8)];
      accs[j] = mfma16(qf[t], kf, accs[j]);
    }

  // register softmax, normalized weights into P (LDS)
  const float rscale = rsqrtf((float)H);
  for (int r = 0; r < 4; ++r) {
    float s[4];
    for (int j = 0; j < 4; ++j) s[j] = accs[j][r] * rscale;
    float mx = fmaxf(fmaxf(s[0], s[1]), fmaxf(s[2], s[3]));
    mx = fmaxf(mx, __shfl_xor(mx, 1));
    mx = fmaxf(mx, __shfl_xor(mx, 2));
    mx = fmaxf(mx, __shfl_xor(mx, 4));
    mx = fmaxf(mx, __shfl_xor(mx, 8));
    float e[4], sum = 0.f;
    for (int j = 0; j < 4; ++j) {
      e[j] = (float)(bf16_t)__expf(s[j] - mx);
      sum += e[j];
    }
    sum += __shfl_xor(sum, 1);
    sum += __shfl_xor(sum, 2);
    sum += __shfl_xor(sum, 4);
    sum += __shfl_xor(sum, 8);
    float rs = 1.f / sum;
    for (int j = 0; j < 4; ++j)
      P[16 * w + qd * 4 + r][16 * j + ln] = (bf16_t)(e[j] * rs);
  }
  __syncthreads();   // drains V (mostly landed) + makes P visible

  // attended = P V via swapped operands: lane holds D[m=16w+ln][nb + r]
  const int m = 16 * w + ln;
  const long obase = ((long)b * S + h * 64 + m) * H;
  for (int nc = 0; nc < 4; ++nc) {
    f32x4 acco[8];
    for (int j = 0; j < 8; ++j) acco[j] = (f32x4){0.f, 0.f, 0.f, 0.f};
    for (int ks = 0; ks < 2; ++ks) {
      bf16x8 pf = *(const bf16x8*)&P[m][ks * 32 + qd * 8];
      for (int j = 0; j < 8; ++j) {
        int row = nc * 128 + 16 * j + ln;
        bf16x8 vf = *(const bf16x8*)&Vs[row * 64 + (((ks * 4 + qd) ^ l7) * 8)];
        acco[j] = mfma16(vf, pf, acco[j]);
      }
    }
    for (int j = 0; j < 8; ++j) {
      int nb = nc * 128 + 16 * j + 4 * qd;
      bf16x4 pk;
      for (int r = 0; r < 4; ++r) pk[r] = (bf16_t)acco[j][r];
      *(bf16x4*)&Att[obase + nb] = pk;
    }
  }
}

extern "C" void kernel_launch(void* const* d_in, const int* in_sizes, int n_in,
                              void* d_out, int out_size, void* d_ws, size_t ws_size,
                              hipStream_t stream)
{
  const float* x  = (const float*)d_in[0];
  const float* Wq = (const float*)d_in[1]; const float* bq = (const float*)d_in[2];
  const float* Wk = (const float*)d_in[3]; const float* bk = (const float*)d_in[4];
  const float* Wv = (const float*)d_in[5]; const float* bv = (const float*)d_in[6];
  const float* Wo = (const float*)d_in[7]; const float* bo = (const float*)d_in[8];
  const int* perm = (const int*)d_in[9];

  const int S = in_sizes[9];                 // 4096
  const int H = in_sizes[2];                 // 512
  const int B = in_sizes[0] / (S * H);       // 8
  const int M = B * S;                       // 32768

  size_t bufB = (size_t)M * H * sizeof(bf16_t);          // 32 MB
  size_t wB   = 4 * (size_t)H * H * sizeof(bf16_t);
  size_t need = 256 + 4 * bufB + wB + 4 * H * 2 + (size_t)S * 4;
  if (ws_size < need) return;

  char* p = (char*)d_ws;  p += 256;
  bf16_t* Xp = (bf16_t*)p;  p += bufB;        // aliased as Att after QKV GEMM
  bf16_t* Qp = (bf16_t*)p;  p += bufB;
  bf16_t* Kp = (bf16_t*)p;  p += bufB;
  bf16_t* Vt = (bf16_t*)p;  p += bufB;        // V^T: [b][head][chan][tok]
  bf16_t* Wb = (bf16_t*)p;  p += wB;
  bf16_t* bb = (bf16_t*)p;  p += 4 * H * 2;
  int* invp  = (int*)p;
  bf16_t* Att = Xp;

  invperm_kernel<<<(S + 255) / 256, 256, 0, stream>>>(perm, invp, S);
  convert_x_kernel<<<(M * H) / 2048, 256, 0, stream>>>(x, Xp, perm, S, H);
  dim3 gw((H * H) / 2048 + 1, 1, 4);
  convert_w_kernel<<<gw, 256, 0, stream>>>(Wq, bq, Wk, bk, Wv, bv, Wo, bo,
                                           Wb, bb, H);

  dim3 g1(M / 256, H / 256, 3);
  gemm_qkv_kernel<<<g1, 512, 0, stream>>>(Xp, Wb, bb, Qp, Kp, Vt, S, H);

  dim3 g2(B * (S / 64));
  attn_kernel<<<g2, 256, 0, stream>>>(Qp, Kp, Vt, Att, S, H);

  dim3 g3(M / 256, H / 256, 1);
  gemm_o_kernel<<<g3, 512, 0, stream>>>(Att, Wb, bb, (float*)d_out, invp, S, H);
}

// Round 4
// 265.061 us; speedup vs baseline: 1.0710x; 1.0082x over previous
//
#include <hip/hip_runtime.h>
#include <hip/hip_bf16.h>

typedef __bf16 bf16_t;
typedef __attribute__((ext_vector_type(8))) __bf16 bf16x8;
typedef __attribute__((ext_vector_type(4))) __bf16 bf16x4;
typedef __attribute__((ext_vector_type(4))) float f32x4;

static __device__ __forceinline__ f32x4 mfma16(bf16x8 a, bf16x8 b, f32x4 c) {
  return __builtin_amdgcn_mfma_f32_16x16x32_bf16(a, b, c, 0, 0, 0);
}

// async global->LDS, 16 B per lane. LDS dest is wave-uniform base + lane*16.
static __device__ __forceinline__ void async16(const void* g, void* l) {
  __builtin_amdgcn_global_load_lds(
      (const __attribute__((address_space(1))) void*)g,
      (__attribute__((address_space(3))) void*)l, 16, 0, 0);
}

static __device__ __forceinline__ bf16x8 load8f(const float* __restrict__ fp) {
  float4 a = *(const float4*)fp;
  float4 b = *(const float4*)(fp + 4);
  bf16x8 r;
  r[0] = (bf16_t)a.x; r[1] = (bf16_t)a.y; r[2] = (bf16_t)a.z; r[3] = (bf16_t)a.w;
  r[4] = (bf16_t)b.x; r[5] = (bf16_t)b.y; r[6] = (bf16_t)b.z; r[7] = (bf16_t)b.w;
  return r;
}

__global__ void invperm_kernel(const int* __restrict__ perm, int* __restrict__ invp, int S) {
  int i = blockIdx.x * 256 + threadIdx.x;
  if (i < S) invp[perm[i]] = i;
}

// x -> bf16, pre-applying the permutation: Xp[b*S+i] = (bf16) x[b*S+perm[i]]
__global__ __launch_bounds__(256) void convert_x_kernel(
    const float* __restrict__ x, bf16_t* __restrict__ Xp,
    const int* __restrict__ perm, int S, int H)
{
  int m = blockIdx.x * 4 + (threadIdx.x >> 6);
  int c = (threadIdx.x & 63) * 8;
  int b = m / S, i = m - b * S;
  long src = ((long)b * S + perm[i]) * H + c;
  *(bf16x8*)&Xp[(long)m * H + c] = load8f(x + src);
}

__global__ __launch_bounds__(256) void convert_w_kernel(
    const float* Wq, const float* bq, const float* Wk, const float* bk,
    const float* Wv, const float* bv, const float* Wo, const float* bo,
    bf16_t* __restrict__ Wb, bf16_t* __restrict__ bb, int H)
{
  const int z = blockIdx.z;
  const float* W  = (z == 0) ? Wq : (z == 1) ? Wk : (z == 2) ? Wv : Wo;
  const float* bi = (z == 0) ? bq : (z == 1) ? bk : (z == 2) ? bv : bo;
  bf16_t* dst = Wb + (long)z * H * H;
  int nwb = (H * H) / 2048;
  if ((int)blockIdx.x < nwb) {
    long e = (long)blockIdx.x * 2048 + threadIdx.x * 8;
    *(bf16x8*)&dst[e] = load8f(W + e);
  } else {
    int e = threadIdx.x * 8;
    if (e < H) *(bf16x8*)&bb[z * H + e] = load8f(bi + e);
  }
}

// ---------------------------------------------------------------------------
// 2-phase/K-tile pipelined GEMM core: C = A * W^T + bias.
// BM=BN=256, BK=64, 512 threads = 8 waves (2M x 4N), per-wave 128x64 output
// (acc[2][2][4][2] f32x4 = 64 VGPR). LDS = 2 slots x (A 32KB + B 32KB) =
// 128 KB, 1 block/CU.
// Per K-tile kt, TWO phases (r3 post-mortem: 4 phases -> 2 halves the
// barrier-pair count per MFMA and removes the redundant B re-read):
//   phase I : ds_read A-half0 (8 b128) + ALL B (8 b128, held in regs across
//             both phases); stage 6 loads {A0,B0,B1} of tile kt+1; barrier;
//             lgkmcnt(0); 32 MFMA (rh=0); GATE vmcnt(6); barrier.
//   phase II: ds_read A-half1 (8 b128); stage 2 loads {A1}; barrier;
//             lgkmcnt(0); 32 MFMA (rh=1); GATE vmcnt(2); barrier.
// Gates sit AFTER the MFMA cluster (stall overlaps the barrier wait, never
// precedes the reads). In-order vmcnt ledger (8 issues/tile/wave:
// I1..I6 @pI = {A0,B0,B1}, I7,I8 @pII = {A1}):
//   END(pI) vmcnt(6): outstanding = prev{I7,I8}+cur{I1..I6}=8 -> forces
//     prev A1 landed; barrier follows; pII reads A1 -> cross-wave RAW safe.
//   END(pII) vmcnt(2): outstanding = cur{I1..I8}=8 -> forces cur {A0,B0,B1}
//     landed; barrier; next tile pI reads them -> safe. Slack ~1.7 phases.
// Last tile: no stages; both gates become vmcnt(0) (first is the real drain).
// WAR: stages target the slot whose last readers finished a full tile ago.
// Chunk-XOR swizzle (chunk' = chunk ^ (row&7)) via pre-swizzled per-lane
// global source + linear LDS dest; read-side XOR cancels since fragment
// row&7 == ln&7. Measured 0 bank conflicts.
// MODE 0: swapped-operand epilogue, packed bf16x4 column stores (Q/K)
// MODE 1: swapped-operand epilogue, packed float4 column stores (final out)
// MODE 2: original-operand epilogue, writes V^T as [b][head][chan][tok]
// GATHER: A row m is gathered from row b*S + invp[m%S] (inverse permutation)
// ---------------------------------------------------------------------------
template<int MODE, bool GATHER>
__device__ __forceinline__ void gemm_core(
    bf16_t (*__restrict__ At)[64],   // [2*256][64]
    bf16_t (*__restrict__ Bt)[64],   // [2*256][64]
    const bf16_t* __restrict__ A, const bf16_t* __restrict__ W,
    const bf16_t* __restrict__ bias, void* __restrict__ C,
    const int* __restrict__ invp, int N, int K, int S)
{
  const int bm = blockIdx.x * 256, bn = blockIdx.y * 256;
  const int tid = threadIdx.x, lane = tid & 63, w = tid >> 6;   // 8 waves
  const int qd = lane >> 4, ln = lane & 15, l7 = ln & 7;
  const int wm = w & 1, wn = w >> 1;            // 2M x 4N wave grid
  const int srow = lane >> 3;                   // 0..7 (row&7 of staged row)
  const int scol = ((lane & 7) ^ srow) * 8;     // swizzled global fetch chunk

  // Stage-group tables. A-half h covers the rh=h 64-row slices of both wave
  // halves; B-half c covers the ch=c 32-row slices of all 4 wn quarters.
  int ga[2][2], gb[2][2];
#pragma unroll
  for (int u = 0; u < 2; ++u) {
    int ix = w + 8 * u;                         // 0..15
    ga[0][u] = (ix & 7) + ((ix >> 3) << 4);
    ga[1][u] = ga[0][u] + 8;
    gb[0][u] = (ix & 3) + ((ix >> 2) << 3);
    gb[1][u] = gb[0][u] + 4;
  }
  long aoff[2][2], woff[2][2];
#pragma unroll
  for (int h = 0; h < 2; ++h)
#pragma unroll
    for (int u = 0; u < 2; ++u) {
      int mg = bm + ga[h][u] * 8 + srow;
      if (GATHER) { int b_ = mg / S; aoff[h][u] = ((long)b_ * S + invp[mg - b_ * S]) * K + scol; }
      else        { aoff[h][u] = (long)mg * K + scol; }
      woff[h][u] = (long)(bn + gb[h][u] * 8 + srow) * K + scol;
    }

  f32x4 acc[2][2][4][2];
#pragma unroll
  for (int a = 0; a < 2; ++a)
#pragma unroll
    for (int b = 0; b < 2; ++b)
#pragma unroll
      for (int i = 0; i < 4; ++i)
#pragma unroll
        for (int j = 0; j < 2; ++j)
          acc[a][b][i][j] = (f32x4){0.f, 0.f, 0.f, 0.f};

  bf16x8 af[4][2], bfr[2][2][2];                 // bfr[ch][j][ks] lives 2 phases
  const int NT = K >> 6;                         // 8 K-tiles for K=512

#define LOAD_A(RH)                                                            \
  _Pragma("unroll") for (int i = 0; i < 4; ++i)                               \
  _Pragma("unroll") for (int ks = 0; ks < 2; ++ks)                            \
    af[i][ks] = *(const bf16x8*)&At[sb + wm * 128 + (RH) * 64 + 16 * i + ln]  \
                                   [((ks * 4 + qd) ^ l7) * 8];
#define LOAD_B(CH)                                                            \
  _Pragma("unroll") for (int j = 0; j < 2; ++j)                               \
  _Pragma("unroll") for (int ks = 0; ks < 2; ++ks)                            \
    bfr[CH][j][ks] = *(const bf16x8*)&Bt[sb + wn * 64 + (CH) * 32 + 16 * j + ln] \
                                        [((ks * 4 + qd) ^ l7) * 8];
#define STAGE_A(HH)                                                           \
  { async16(&A[aoff[HH][0] + k2], &At[so + ga[HH][0] * 8][0]);                \
    async16(&A[aoff[HH][1] + k2], &At[so + ga[HH][1] * 8][0]); }
#define STAGE_B(CH)                                                           \
  { async16(&W[woff[CH][0] + k2], &Bt[so + gb[CH][0] * 8][0]);                \
    async16(&W[woff[CH][1] + k2], &Bt[so + gb[CH][1] * 8][0]); }
#define MFMA32(RH)                                                            \
  __builtin_amdgcn_s_setprio(1);                                              \
  _Pragma("unroll") for (int ch = 0; ch < 2; ++ch)                            \
  _Pragma("unroll") for (int i = 0; i < 4; ++i)                               \
  _Pragma("unroll") for (int j = 0; j < 2; ++j)                               \
  _Pragma("unroll") for (int ks = 0; ks < 2; ++ks) {                          \
    if (MODE == 2) acc[RH][ch][i][j] = mfma16(af[i][ks], bfr[ch][j][ks], acc[RH][ch][i][j]); \
    else           acc[RH][ch][i][j] = mfma16(bfr[ch][j][ks], af[i][ks], acc[RH][ch][i][j]); \
  }                                                                           \
  __builtin_amdgcn_s_setprio(0);
#define GATE(N) asm volatile("s_waitcnt vmcnt(" #N ")" ::: "memory")
#define PH_MID                                                                \
  __builtin_amdgcn_s_barrier();                                               \
  asm volatile("s_waitcnt lgkmcnt(0)" ::: "memory");
#define PH_END __builtin_amdgcn_s_barrier();

  // prologue: stage tile 0 into slot 0, issue order A0,B0,B1 (pI needs) then
  // A1 (pII needs); gate vmcnt(2) forces the first 6; barrier.
  async16(&A[aoff[0][0]], &At[ga[0][0] * 8][0]);
  async16(&A[aoff[0][1]], &At[ga[0][1] * 8][0]);
  async16(&W[woff[0][0]], &Bt[gb[0][0] * 8][0]);
  async16(&W[woff[0][1]], &Bt[gb[0][1] * 8][0]);
  async16(&W[woff[1][0]], &Bt[gb[1][0] * 8][0]);
  async16(&W[woff[1][1]], &Bt[gb[1][1] * 8][0]);
  async16(&A[aoff[1][0]], &At[ga[1][0] * 8][0]);
  async16(&A[aoff[1][1]], &At[ga[1][1] * 8][0]);
  GATE(2);
  __builtin_amdgcn_s_barrier();

  for (int kt = 0; kt < NT; ++kt) {
    const int sb = (kt & 1) << 8;          // compute-slot row base
    const int so = ((kt + 1) & 1) << 8;    // stage-slot row base
    const long k2 = (long)(kt + 1) << 6;
    const bool st = (kt + 1 < NT);

    // ---- phase I: rh=0, all B ----
    LOAD_A(0)
    LOAD_B(0)
    LOAD_B(1)
    if (st) { STAGE_A(0) STAGE_B(0) STAGE_B(1) }   // issues I1..I6
    PH_MID
    MFMA32(0)
    if (st) { GATE(6); } else { GATE(0); }         // force prev tile's A1
    PH_END
    // ---- phase II: rh=1, B reused from regs ----
    LOAD_A(1)
    if (st) { STAGE_A(1) }                          // issues I7,I8
    PH_MID
    MFMA32(1)
    if (st) { GATE(2); } else { GATE(0); }         // force this tile's I1..I6
    PH_END
  }

#undef LOAD_A
#undef LOAD_B
#undef STAGE_A
#undef STAGE_B
#undef MFMA32
#undef GATE
#undef PH_MID
#undef PH_END

  if (MODE == 2) {
    // lane holds C[m = bm+wm*128+rh*64+16i+4qd+r][n = bn+wn*64+ch*32+16j+ln];
    // write V^T packed along tokens: Vt[(b*heads+h)*N + n][tok].
    const int heads = S >> 6;
    const int b_ = bm / S;
    const int ip0 = bm - b_ * S;
#pragma unroll
    for (int rh = 0; rh < 2; ++rh)
#pragma unroll
      for (int ch = 0; ch < 2; ++ch)
#pragma unroll
        for (int j = 0; j < 2; ++j) {
          int n = bn + wn * 64 + ch * 32 + 16 * j + ln;
          float bv = (float)bias[n];
#pragma unroll
          for (int i = 0; i < 4; ++i) {
            int il = ip0 + wm * 128 + rh * 64 + 16 * i + 4 * qd;
            int h = il >> 6, tok = il & 63;
            bf16x4 pk;
#pragma unroll
            for (int r = 0; r < 4; ++r) pk[r] = (bf16_t)(acc[rh][ch][i][j][r] + bv);
            *(bf16x4*)&((bf16_t*)C)[(((long)(b_ * heads + h) * N + n) << 6) + tok] = pk;
          }
        }
  } else {
    // swapped: lane holds C[m = bm+wm*128+rh*64+16i+ln][n = bn+wn*64+ch*32+16j+4qd+r]
#pragma unroll
    for (int rh = 0; rh < 2; ++rh)
#pragma unroll
      for (int ch = 0; ch < 2; ++ch)
#pragma unroll
        for (int j = 0; j < 2; ++j) {
          int nb = bn + wn * 64 + ch * 32 + 16 * j + 4 * qd;
          bf16x4 b4 = *(const bf16x4*)&bias[nb];
#pragma unroll
          for (int i = 0; i < 4; ++i) {
            int m = bm + wm * 128 + rh * 64 + 16 * i + ln;
            if (MODE == 1) {
              float4 pk = {acc[rh][ch][i][j][0] + (float)b4[0], acc[rh][ch][i][j][1] + (float)b4[1],
                           acc[rh][ch][i][j][2] + (float)b4[2], acc[rh][ch][i][j][3] + (float)b4[3]};
              *(float4*)&((float*)C)[(long)m * N + nb] = pk;
            } else {
              bf16x4 pk;
#pragma unroll
              for (int r = 0; r < 4; ++r) pk[r] = (bf16_t)(acc[rh][ch][i][j][r] + (float)b4[r]);
              *(bf16x4*)&((bf16_t*)C)[(long)m * N + nb] = pk;
            }
          }
        }
  }
}

__global__ __launch_bounds__(512, 2) void gemm_qkv_kernel(
    const bf16_t* __restrict__ Xp, const bf16_t* __restrict__ Wb,
    const bf16_t* __restrict__ bb,
    bf16_t* __restrict__ Qp, bf16_t* __restrict__ Kp, bf16_t* __restrict__ Vt,
    int S, int H)
{
  __shared__ bf16_t At[512][64];   // 64 KB (2 slots x 256 rows)
  __shared__ bf16_t Bt[512][64];   // 64 KB
  const int z = blockIdx.z;
  if (z < 2)
    gemm_core<0, false>(At, Bt, Xp, Wb + (long)z * H * H, bb + z * H,
                        z ? (void*)Kp : (void*)Qp, nullptr, H, H, S);
  else
    gemm_core<2, false>(At, Bt, Xp, Wb + 2L * H * H, bb + 2 * H, Vt, nullptr, H, H, S);
}

__global__ __launch_bounds__(512, 2) void gemm_o_kernel(
    const bf16_t* __restrict__ Att, const bf16_t* __restrict__ Wb,
    const bf16_t* __restrict__ bb, float* __restrict__ C,
    const int* __restrict__ invp, int S, int H)
{
  __shared__ bf16_t At[512][64];
  __shared__ bf16_t Bt[512][64];
  gemm_core<1, true>(At, Bt, Att, Wb + 3L * H * H, bb + 3 * H, C, invp, H, H, S);
}

// One block per (b, head). K and V^T slabs in SEPARATE LDS regions: V asyncs
// are issued right after the K barrier so their latency overlaps the QK MFMA
// phase; the pre-PV barrier drains V cheaply. 137 KB LDS -> 1 block/CU.
__global__ __launch_bounds__(256) void attn_kernel(
    const bf16_t* __restrict__ Qp, const bf16_t* __restrict__ Kp,
    const bf16_t* __restrict__ Vt, bf16_t* __restrict__ Att,
    int S, int H)
{
  const int heads = S >> 6;
  const int b = blockIdx.x / heads;
  const int h = blockIdx.x % heads;
  const long qkbase = ((long)b * S + h * 64) * H;
  const long vbase  = (long)(b * heads + h) * H * 64;

  const int tid = threadIdx.x, lane = tid & 63, w = tid >> 6;
  const int qd = lane >> 4, ln = lane & 15;
  const int l7 = ln & 7;

  __shared__ bf16_t Ks[64 * 512];   // 64 KB K slab
  __shared__ bf16_t Vs[512 * 64];   // 64 KB V^T slab (separate: enables overlap)
  __shared__ bf16_t P[64][72];      // softmax weights

  // stage K: one full row (512 bf16) per instr, low-3 chunk swizzle
  for (int r0 = 0; r0 < 16; ++r0) {
    int row = 16 * w + r0;
    async16(&Kp[qkbase + (long)row * H + (lane ^ (row & 7)) * 8], &Ks[row * 512]);
  }
  bf16x8 qf[16];
  for (int t = 0; t < 16; ++t)
    qf[t] = *(const bf16x8*)&Qp[qkbase + (long)(16 * w + ln) * H + t * 32 + qd * 8];
  __syncthreads();            // drains K (and Q frags)

  // issue V^T staging NOW; it completes during the QK/softmax phase
  for (int u = 0; u < 16; ++u) {
    int rowb = 128 * w + 8 * u;
    async16(&Vt[vbase + (long)(rowb + (lane >> 3)) * 64 +
                (((lane & 7) ^ ((lane >> 3) & 7)) * 8)],
            &Vs[rowb * 64]);
  }

  // scores = Q K^T; lane (w,qd,ln) gets S[16w+4qd+r][16j+ln]
  f32x4 accs[4];
  for (int j = 0; j < 4; ++j) accs[j] = (f32x4){0.f, 0.f, 0.f, 0.f};
  for (int t = 0; t < 16; ++t)
    for (int j = 0; j < 4; ++j) {
      bf16x8 kf = *(const bf16x8*)&Ks[(16 * j + ln) * 512 + (((t * 4 + qd) ^ l7) * 8)];
      accs[j] = mfma16(qf[t], kf, accs[j]);
    }

  // register softmax, normalized weights into P (LDS)
  const float rscale = rsqrtf((float)H);
  for (int r = 0; r < 4; ++r) {
    float s[4];
    for (int j = 0; j < 4; ++j) s[j] = accs[j][r] * rscale;
    float mx = fmaxf(fmaxf(s[0], s[1]), fmaxf(s[2], s[3]));
    mx = fmaxf(mx, __shfl_xor(mx, 1));
    mx = fmaxf(mx, __shfl_xor(mx, 2));
    mx = fmaxf(mx, __shfl_xor(mx, 4));
    mx = fmaxf(mx, __shfl_xor(mx, 8));
    float e[4], sum = 0.f;
    for (int j = 0; j < 4; ++j) {
      e[j] = (float)(bf16_t)__expf(s[j] - mx);
      sum += e[j];
    }
    sum += __shfl_xor(sum, 1);
    sum += __shfl_xor(sum, 2);
    sum += __shfl_xor(sum, 4);
    sum += __shfl_xor(sum, 8);
    float rs = 1.f / sum;
    for (int j = 0; j < 4; ++j)
      P[16 * w + qd * 4 + r][16 * j + ln] = (bf16_t)(e[j] * rs);
  }
  __syncthreads();   // drains V (mostly landed) + makes P visible

  // attended = P V via swapped operands: lane holds D[m=16w+ln][nb + r]
  const int m = 16 * w + ln;
  const long obase = ((long)b * S + h * 64 + m) * H;
  for (int nc = 0; nc < 4; ++nc) {
    f32x4 acco[8];
    for (int j = 0; j < 8; ++j) acco[j] = (f32x4){0.f, 0.f, 0.f, 0.f};
    for (int ks = 0; ks < 2; ++ks) {
      bf16x8 pf = *(const bf16x8*)&P[m][ks * 32 + qd * 8];
      for (int j = 0; j < 8; ++j) {
        int row = nc * 128 + 16 * j + ln;
        bf16x8 vf = *(const bf16x8*)&Vs[row * 64 + (((ks * 4 + qd) ^ l7) * 8)];
        acco[j] = mfma16(vf, pf, acco[j]);
      }
    }
    for (int j = 0; j < 8; ++j) {
      int nb = nc * 128 + 16 * j + 4 * qd;
      bf16x4 pk;
      for (int r = 0; r < 4; ++r) pk[r] = (bf16_t)acco[j][r];
      *(bf16x4*)&Att[obase + nb] = pk;
    }
  }
}

extern "C" void kernel_launch(void* const* d_in, const int* in_sizes, int n_in,
                              void* d_out, int out_size, void* d_ws, size_t ws_size,
                              hipStream_t stream)
{
  const float* x  = (const float*)d_in[0];
  const float* Wq = (const float*)d_in[1]; const float* bq = (const float*)d_in[2];
  const float* Wk = (const float*)d_in[3]; const float* bk = (const float*)d_in[4];
  const float* Wv = (const float*)d_in[5]; const float* bv = (const float*)d_in[6];
  const float* Wo = (const float*)d_in[7]; const float* bo = (const float*)d_in[8];
  const int* perm = (const int*)d_in[9];

  const int S = in_sizes[9];                 // 4096
  const int H = in_sizes[2];                 // 512
  const int B = in_sizes[0] / (S * H);       // 8
  const int M = B * S;                       // 32768

  size_t bufB = (size_t)M * H * sizeof(bf16_t);          // 32 MB
  size_t wB   = 4 * (size_t)H * H * sizeof(bf16_t);
  size_t need = 256 + 4 * bufB + wB + 4 * H * 2 + (size_t)S * 4;
  if (ws_size < need) return;

  char* p = (char*)d_ws;  p += 256;
  bf16_t* Xp = (bf16_t*)p;  p += bufB;        // aliased as Att after QKV GEMM
  bf16_t* Qp = (bf16_t*)p;  p += bufB;
  bf16_t* Kp = (bf16_t*)p;  p += bufB;
  bf16_t* Vt = (bf16_t*)p;  p += bufB;        // V^T: [b][head][chan][tok]
  bf16_t* Wb = (bf16_t*)p;  p += wB;
  bf16_t* bb = (bf16_t*)p;  p += 4 * H * 2;
  int* invp  = (int*)p;
  bf16_t* Att = Xp;

  invperm_kernel<<<(S + 255) / 256, 256, 0, stream>>>(perm, invp, S);
  convert_x_kernel<<<(M * H) / 2048, 256, 0, stream>>>(x, Xp, perm, S, H);
  dim3 gw((H * H) / 2048 + 1, 1, 4);
  convert_w_kernel<<<gw, 256, 0, stream>>>(Wq, bq, Wk, bk, Wv, bv, Wo, bo,
                                           Wb, bb, H);

  dim3 g1(M / 256, H / 256, 3);
  gemm_qkv_kernel<<<g1, 512, 0, stream>>>(Xp, Wb, bb, Qp, Kp, Vt, S, H);

  dim3 g2(B * (S / 64));
  attn_kernel<<<g2, 256, 0, stream>>>(Qp, Kp, Vt, Att, S, H);

  dim3 g3(M / 256, H / 256, 1);
  gemm_o_kernel<<<g3, 512, 0, stream>>>(Att, Wb, bb, (float*)d_out, invp, S, H);
}

// Round 5
// 255.934 us; speedup vs baseline: 1.1092x; 1.0357x over previous
//
#include <hip/hip_runtime.h>
#include <hip/hip_bf16.h>

typedef __bf16 bf16_t;
typedef __attribute__((ext_vector_type(8))) __bf16 bf16x8;
typedef __attribute__((ext_vector_type(4))) __bf16 bf16x4;
typedef __attribute__((ext_vector_type(4))) float f32x4;

static __device__ __forceinline__ f32x4 mfma16(bf16x8 a, bf16x8 b, f32x4 c) {
  return __builtin_amdgcn_mfma_f32_16x16x32_bf16(a, b, c, 0, 0, 0);
}

// async global->LDS, 16 B per lane. LDS dest is wave-uniform base + lane*16.
static __device__ __forceinline__ void async16(const void* g, void* l) {
  __builtin_amdgcn_global_load_lds(
      (const __attribute__((address_space(1))) void*)g,
      (__attribute__((address_space(3))) void*)l, 16, 0, 0);
}

static __device__ __forceinline__ bf16x8 load8f(const float* __restrict__ fp) {
  float4 a = *(const float4*)fp;
  float4 b = *(const float4*)(fp + 4);
  bf16x8 r;
  r[0] = (bf16_t)a.x; r[1] = (bf16_t)a.y; r[2] = (bf16_t)a.z; r[3] = (bf16_t)a.w;
  r[4] = (bf16_t)b.x; r[5] = (bf16_t)b.y; r[6] = (bf16_t)b.z; r[7] = (bf16_t)b.w;
  return r;
}

__global__ void invperm_kernel(const int* __restrict__ perm, int* __restrict__ invp, int S) {
  int i = blockIdx.x * 256 + threadIdx.x;
  if (i < S) invp[perm[i]] = i;
}

// x -> bf16, pre-applying the permutation: Xp[b*S+i] = (bf16) x[b*S+perm[i]]
__global__ __launch_bounds__(256) void convert_x_kernel(
    const float* __restrict__ x, bf16_t* __restrict__ Xp,
    const int* __restrict__ perm, int S, int H)
{
  int m = blockIdx.x * 4 + (threadIdx.x >> 6);
  int c = (threadIdx.x & 63) * 8;
  int b = m / S, i = m - b * S;
  long src = ((long)b * S + perm[i]) * H + c;
  *(bf16x8*)&Xp[(long)m * H + c] = load8f(x + src);
}

__global__ __launch_bounds__(256) void convert_w_kernel(
    const float* Wq, const float* bq, const float* Wk, const float* bk,
    const float* Wv, const float* bv, const float* Wo, const float* bo,
    bf16_t* __restrict__ Wb, bf16_t* __restrict__ bb, int H)
{
  const int z = blockIdx.z;
  const float* W  = (z == 0) ? Wq : (z == 1) ? Wk : (z == 2) ? Wv : Wo;
  const float* bi = (z == 0) ? bq : (z == 1) ? bk : (z == 2) ? bv : bo;
  bf16_t* dst = Wb + (long)z * H * H;
  int nwb = (H * H) / 2048;
  if ((int)blockIdx.x < nwb) {
    long e = (long)blockIdx.x * 2048 + threadIdx.x * 8;
    *(bf16x8*)&dst[e] = load8f(W + e);
  } else {
    int e = threadIdx.x * 8;
    if (e < H) *(bf16x8*)&bb[z * H + e] = load8f(bi + e);
  }
}

// ---------------------------------------------------------------------------
// GEMM core: r3's 4-phase/K-tile counted-vmcnt pipeline (best measured:
// 79.5us) + NEW coalesced LDS-transpose epilogues (r4 theory: row-scattered
// epilogue stores - 64 cache lines per wave instr - were the schedule-
// independent drag; all K-loop variants sat at 80-97us with nothing
// saturated).
// BM=BN=256, BK=64, 512 threads = 8 waves (2M x 4N). LDS: one 128 KB block;
// K-loop carves 2 slots x (A 32KB + B 32KB); epilogue reuses all 128 KB as a
// 16B-granular XOR-swizzled transpose scratch, then stores contiguous 1 KB
// runs per wave instr (16 dense lines vs 64 scattered).
// MODE 0: bf16 C tile, row-major out (Q/K)
// MODE 1: f32 C tile (final out), two 64KB halves through scratch
// MODE 2: writes V^T as [b][head][chan][tok], via transposed scratch
// GATHER: A row m is gathered from row b*S + invp[m%S]
// ---------------------------------------------------------------------------
template<int MODE, bool GATHER>
__device__ __forceinline__ void gemm_core(
    unsigned char* __restrict__ smem,   // 128 KB
    const bf16_t* __restrict__ A, const bf16_t* __restrict__ W,
    const bf16_t* __restrict__ bias, void* __restrict__ C,
    const int* __restrict__ invp, int N, int K, int S)
{
  bf16_t (*At)[64] = (bf16_t(*)[64])smem;             // [512][64]
  bf16_t (*Bt)[64] = (bf16_t(*)[64])(smem + 65536);   // [512][64]

  const int bm = blockIdx.x * 256, bn = blockIdx.y * 256;
  const int tid = threadIdx.x, lane = tid & 63, w = tid >> 6;   // 8 waves
  const int qd = lane >> 4, ln = lane & 15, l7 = ln & 7;
  const int wm = w & 1, wn = w >> 1;            // 2M x 4N wave grid
  const int srow = lane >> 3;                   // 0..7 (row&7 of staged row)
  const int scol = ((lane & 7) ^ srow) * 8;     // swizzled global fetch chunk

  int ga[2][2], gb[2][2];
#pragma unroll
  for (int u = 0; u < 2; ++u) {
    int ix = w + 8 * u;                         // 0..15
    ga[0][u] = (ix & 7) + ((ix >> 3) << 4);
    ga[1][u] = ga[0][u] + 8;
    gb[0][u] = (ix & 3) + ((ix >> 2) << 3);
    gb[1][u] = gb[0][u] + 4;
  }
  long aoff[2][2], woff[2][2];
#pragma unroll
  for (int h = 0; h < 2; ++h)
#pragma unroll
    for (int u = 0; u < 2; ++u) {
      int mg = bm + ga[h][u] * 8 + srow;
      if (GATHER) { int b_ = mg / S; aoff[h][u] = ((long)b_ * S + invp[mg - b_ * S]) * K + scol; }
      else        { aoff[h][u] = (long)mg * K + scol; }
      woff[h][u] = (long)(bn + gb[h][u] * 8 + srow) * K + scol;
    }

  f32x4 acc[2][2][4][2];
#pragma unroll
  for (int a = 0; a < 2; ++a)
#pragma unroll
    for (int b = 0; b < 2; ++b)
#pragma unroll
      for (int i = 0; i < 4; ++i)
#pragma unroll
        for (int j = 0; j < 2; ++j)
          acc[a][b][i][j] = (f32x4){0.f, 0.f, 0.f, 0.f};

  bf16x8 af[4][2], bfr[2][2];
  const int NT = K >> 6;                         // 8 K-tiles for K=512

#define LOAD_A(RH)                                                            \
  _Pragma("unroll") for (int i = 0; i < 4; ++i)                               \
  _Pragma("unroll") for (int ks = 0; ks < 2; ++ks)                            \
    af[i][ks] = *(const bf16x8*)&At[sb + wm * 128 + (RH) * 64 + 16 * i + ln]  \
                                   [((ks * 4 + qd) ^ l7) * 8];
#define LOAD_B(CH)                                                            \
  _Pragma("unroll") for (int j = 0; j < 2; ++j)                               \
  _Pragma("unroll") for (int ks = 0; ks < 2; ++ks)                            \
    bfr[j][ks] = *(const bf16x8*)&Bt[sb + wn * 64 + (CH) * 32 + 16 * j + ln]  \
                                    [((ks * 4 + qd) ^ l7) * 8];
#define STAGE_A(HH)                                                           \
  if (st) {                                                                   \
    async16(&A[aoff[HH][0] + k2], &At[so + ga[HH][0] * 8][0]);                \
    async16(&A[aoff[HH][1] + k2], &At[so + ga[HH][1] * 8][0]);                \
  }
#define STAGE_B(CH)                                                           \
  if (st) {                                                                   \
    async16(&W[woff[CH][0] + k2], &Bt[so + gb[CH][0] * 8][0]);                \
    async16(&W[woff[CH][1] + k2], &Bt[so + gb[CH][1] * 8][0]);                \
  }
#define MFMA_Q(RH, CH)                                                        \
  __builtin_amdgcn_s_setprio(1);                                              \
  _Pragma("unroll") for (int i = 0; i < 4; ++i)                               \
  _Pragma("unroll") for (int j = 0; j < 2; ++j)                               \
  _Pragma("unroll") for (int ks = 0; ks < 2; ++ks) {                          \
    if (MODE == 2) acc[RH][CH][i][j] = mfma16(af[i][ks], bfr[j][ks], acc[RH][CH][i][j]); \
    else           acc[RH][CH][i][j] = mfma16(bfr[j][ks], af[i][ks], acc[RH][CH][i][j]); \
  }                                                                           \
  __builtin_amdgcn_s_setprio(0);
#define GATE2 asm volatile("s_waitcnt vmcnt(2)" ::: "memory")
#define GATE0 asm volatile("s_waitcnt vmcnt(0)" ::: "memory")
#define PH_MID                                                                \
  __builtin_amdgcn_s_barrier();                                               \
  asm volatile("s_waitcnt lgkmcnt(0)" ::: "memory");
#define PH_END __builtin_amdgcn_s_barrier();

  // prologue: stage tile 0 into slot 0 in deadline order A0,B0,B1,A1
  async16(&A[aoff[0][0]], &At[ga[0][0] * 8][0]);
  async16(&A[aoff[0][1]], &At[ga[0][1] * 8][0]);
  async16(&W[woff[0][0]], &Bt[gb[0][0] * 8][0]);
  async16(&W[woff[0][1]], &Bt[gb[0][1] * 8][0]);
  async16(&W[woff[1][0]], &Bt[gb[1][0] * 8][0]);
  async16(&W[woff[1][1]], &Bt[gb[1][1] * 8][0]);
  async16(&A[aoff[1][0]], &At[ga[1][0] * 8][0]);
  async16(&A[aoff[1][1]], &At[ga[1][1] * 8][0]);
  GATE2;
  __builtin_amdgcn_s_barrier();

  for (int kt = 0; kt < NT; ++kt) {
    const int sb = (kt & 1) << 8;          // compute-slot row base
    const int so = ((kt + 1) & 1) << 8;    // stage-slot row base
    const long k2 = (long)(kt + 1) << 6;
    const bool st = (kt + 1 < NT);

    // ---- phase 1: (rh=0, ch=0) ----
    GATE2;
    LOAD_A(0)
    LOAD_B(0)
    STAGE_A(0)
    PH_MID
    MFMA_Q(0, 0)
    PH_END
    // ---- phase 2: (rh=0, ch=1) ----
    if (st) { GATE2; } else { GATE0; }     // last tile: drain once here
    LOAD_B(1)
    STAGE_B(0)
    PH_MID
    MFMA_Q(0, 1)
    PH_END
    // ---- phase 3: (rh=1, ch=1) ----
    if (st) { GATE2; }
    LOAD_A(1)
    STAGE_B(1)
    PH_MID
    MFMA_Q(1, 1)
    PH_END
    // ---- phase 4: (rh=1, ch=0) ----
    if (st) { GATE2; }
    LOAD_B(0)
    STAGE_A(1)
    PH_MID
    MFMA_Q(1, 0)
    PH_END
  }

#undef LOAD_A
#undef LOAD_B
#undef STAGE_A
#undef STAGE_B
#undef MFMA_Q
#undef GATE2
#undef GATE0
#undef PH_MID
#undef PH_END

  // ---- coalesced epilogues via 16B-swizzled LDS transpose scratch ----
  // swizzle: 16B chunk index c stored at c' = c ^ (row & 7); read with same
  // XOR. Last K-loop barrier precedes this -> smem reuse is safe.
  if (MODE == 0) {
    // scratch: [256 rows (m)][512 B = 32 chunk16]. lane holds
    // C[m=wm*128+rh*64+16i+ln][n=wn*64+ch*32+16j+4qd+r] (swapped layout).
#pragma unroll
    for (int rh = 0; rh < 2; ++rh)
#pragma unroll
      for (int ch = 0; ch < 2; ++ch)
#pragma unroll
        for (int j = 0; j < 2; ++j) {
          bf16x4 b4 = *(const bf16x4*)&bias[bn + wn * 64 + ch * 32 + 16 * j + 4 * qd];
          int c16 = wn * 8 + ch * 4 + 2 * j + (qd >> 1);
#pragma unroll
          for (int i = 0; i < 4; ++i) {
            int m = wm * 128 + rh * 64 + 16 * i + ln;
            bf16x4 pk;
#pragma unroll
            for (int r = 0; r < 4; ++r) pk[r] = (bf16_t)(acc[rh][ch][i][j][r] + (float)b4[r]);
            *(bf16x4*)(smem + m * 512 + ((c16 ^ l7) * 16) + (qd & 1) * 8) = pk;
          }
        }
    __syncthreads();
#pragma unroll
    for (int k = 0; k < 16; ++k) {
      int row = w * 32 + 2 * k + (lane >> 5);
      int c = lane & 31;
      bf16x8 v = *(const bf16x8*)(smem + row * 512 + ((c ^ (row & 7)) * 16));
      *(bf16x8*)&((bf16_t*)C)[(long)(bm + row) * N + bn + c * 8] = v;
    }
  } else if (MODE == 1) {
    // f32 out: two halves (rh), each 128 rows x 1 KB through scratch.
#pragma unroll
    for (int rh = 0; rh < 2; ++rh) {
      if (rh) __syncthreads();             // half-0 reads done before reuse
#pragma unroll
      for (int ch = 0; ch < 2; ++ch)
#pragma unroll
        for (int j = 0; j < 2; ++j) {
          bf16x4 b4 = *(const bf16x4*)&bias[bn + wn * 64 + ch * 32 + 16 * j + 4 * qd];
          int c16 = wn * 16 + ch * 8 + 4 * j + qd;
#pragma unroll
          for (int i = 0; i < 4; ++i) {
            int hrow = wm * 64 + 16 * i + ln;
            float4 pk = {acc[rh][ch][i][j][0] + (float)b4[0], acc[rh][ch][i][j][1] + (float)b4[1],
                         acc[rh][ch][i][j][2] + (float)b4[2], acc[rh][ch][i][j][3] + (float)b4[3]};
            *(float4*)(smem + hrow * 1024 + ((c16 ^ l7) * 16)) = pk;
          }
        }
      __syncthreads();
#pragma unroll
      for (int k = 0; k < 16; ++k) {
        int hrow = w + 8 * k;
        float4 v = *(const float4*)(smem + hrow * 1024 + (((lane) ^ (hrow & 7)) * 16));
        int gm = bm + (hrow >> 6) * 128 + rh * 64 + (hrow & 63);
        *(float4*)&((float*)C)[(long)gm * N + bn + lane * 4] = v;
      }
    }
  } else {
    // MODE 2: transposed scratch Ct[n=256 rows][m=256 cols, 512 B = 32 c16].
    // Non-swapped layout: lane holds C[m=wm*128+rh*64+16i+4qd+r][n=...16j+ln].
    const int heads = S >> 6;
    const int b_ = bm / S;
    const int h0 = (bm - b_ * S) >> 6;          // head base of this block
#pragma unroll
    for (int rh = 0; rh < 2; ++rh)
#pragma unroll
      for (int ch = 0; ch < 2; ++ch)
#pragma unroll
        for (int j = 0; j < 2; ++j) {
          int n = wn * 64 + ch * 32 + 16 * j + ln;
          float bv = (float)bias[bn + n];
#pragma unroll
          for (int i = 0; i < 4; ++i) {
            int c16 = wm * 16 + rh * 8 + 2 * i + (qd >> 1);
            bf16x4 pk;
#pragma unroll
            for (int r = 0; r < 4; ++r) pk[r] = (bf16_t)(acc[rh][ch][i][j][r] + bv);
            *(bf16x4*)(smem + n * 512 + ((c16 ^ l7) * 16) + (qd & 1) * 8) = pk;
          }
        }
    __syncthreads();
#pragma unroll
    for (int k = 0; k < 16; ++k) {
      int h4 = k >> 2;                            // local head (m block)
      int n = (w + 8 * (k & 3)) * 8 + (lane >> 3);
      int tc = lane & 7;                          // 16B tok-chunk
      bf16x8 v = *(const bf16x8*)(smem + n * 512 + (((h4 * 8 + tc) ^ (n & 7)) * 16));
      *(bf16x8*)&((bf16_t*)C)[(((long)(b_ * heads + h0 + h4) * N + bn + n) << 6) + tc * 8] = v;
    }
  }
}

__global__ __launch_bounds__(512, 2) void gemm_qkv_kernel(
    const bf16_t* __restrict__ Xp, const bf16_t* __restrict__ Wb,
    const bf16_t* __restrict__ bb,
    bf16_t* __restrict__ Qp, bf16_t* __restrict__ Kp, bf16_t* __restrict__ Vt,
    int S, int H)
{
  __shared__ __align__(16) unsigned char smem[131072];
  const int z = blockIdx.z;
  if (z < 2)
    gemm_core<0, false>(smem, Xp, Wb + (long)z * H * H, bb + z * H,
                        z ? (void*)Kp : (void*)Qp, nullptr, H, H, S);
  else
    gemm_core<2, false>(smem, Xp, Wb + 2L * H * H, bb + 2 * H, Vt, nullptr, H, H, S);
}

__global__ __launch_bounds__(512, 2) void gemm_o_kernel(
    const bf16_t* __restrict__ Att, const bf16_t* __restrict__ Wb,
    const bf16_t* __restrict__ bb, float* __restrict__ C,
    const int* __restrict__ invp, int S, int H)
{
  __shared__ __align__(16) unsigned char smem[131072];
  gemm_core<1, true>(smem, Att, Wb + 3L * H * H, bb + 3 * H, C, invp, H, H, S);
}

// One block per (b, head). K and V^T slabs in SEPARATE LDS regions: V asyncs
// are issued right after the K barrier so their latency overlaps the QK MFMA
// phase. NEW: output goes through a swizzled LDS transpose (reusing the dead
// Ks slab) so global stores are contiguous 1 KB runs per wave instr.
__global__ __launch_bounds__(256) void attn_kernel(
    const bf16_t* __restrict__ Qp, const bf16_t* __restrict__ Kp,
    const bf16_t* __restrict__ Vt, bf16_t* __restrict__ Att,
    int S, int H)
{
  const int heads = S >> 6;
  const int b = blockIdx.x / heads;
  const int h = blockIdx.x % heads;
  const long qkbase = ((long)b * S + h * 64) * H;
  const long vbase  = (long)(b * heads + h) * H * 64;

  const int tid = threadIdx.x, lane = tid & 63, w = tid >> 6;
  const int qd = lane >> 4, ln = lane & 15;
  const int l7 = ln & 7;

  __shared__ bf16_t Ks[64 * 512];   // 64 KB K slab; reused as out-scratch
  __shared__ bf16_t Vs[512 * 64];   // 64 KB V^T slab
  __shared__ bf16_t P[64][72];      // softmax weights

  // stage K: one full row (512 bf16) per instr, low-3 chunk swizzle
  for (int r0 = 0; r0 < 16; ++r0) {
    int row = 16 * w + r0;
    async16(&Kp[qkbase + (long)row * H + (lane ^ (row & 7)) * 8], &Ks[row * 512]);
  }
  bf16x8 qf[16];
  for (int t = 0; t < 16; ++t)
    qf[t] = *(const bf16x8*)&Qp[qkbase + (long)(16 * w + ln) * H + t * 32 + qd * 8];
  __syncthreads();            // drains K (and Q frags)

  // issue V^T staging NOW; it completes during the QK/softmax phase
  for (int u = 0; u < 16; ++u) {
    int rowb = 128 * w + 8 * u;
    async16(&Vt[vbase + (long)(rowb + (lane >> 3)) * 64 +
                (((lane & 7) ^ ((lane >> 3) & 7)) * 8)],
            &Vs[rowb * 64]);
  }

  // scores = Q K^T; lane (w,qd,ln) gets S[16w+4qd+r][16j+ln]
  f32x4 accs[4];
  for (int j = 0; j < 4; ++j) accs[j] = (f32x4){0.f, 0.f, 0.f, 0.f};
  for (int t = 0; t < 16; ++t)
    for (int j = 0; j < 4; ++j) {
      bf16x8 kf = *(const bf16x8*)&Ks[(16 * j + ln) * 512 + (((t * 4 + qd) ^ l7) * 8)];
      accs[j] = mfma16(qf[t], kf, accs[j]);
    }

  // register softmax, normalized weights into P (LDS)
  const float rscale = rsqrtf((float)H);
  for (int r = 0; r < 4; ++r) {
    float s[4];
    for (int j = 0; j < 4; ++j) s[j] = accs[j][r] * rscale;
    float mx = fmaxf(fmaxf(s[0], s[1]), fmaxf(s[2], s[3]));
    mx = fmaxf(mx, __shfl_xor(mx, 1));
    mx = fmaxf(mx, __shfl_xor(mx, 2));
    mx = fmaxf(mx, __shfl_xor(mx, 4));
    mx = fmaxf(mx, __shfl_xor(mx, 8));
    float e[4], sum = 0.f;
    for (int j = 0; j < 4; ++j) {
      e[j] = (float)(bf16_t)__expf(s[j] - mx);
      sum += e[j];
    }
    sum += __shfl_xor(sum, 1);
    sum += __shfl_xor(sum, 2);
    sum += __shfl_xor(sum, 4);
    sum += __shfl_xor(sum, 8);
    float rs = 1.f / sum;
    for (int j = 0; j < 4; ++j)
      P[16 * w + qd * 4 + r][16 * j + ln] = (bf16_t)(e[j] * rs);
  }
  __syncthreads();   // drains V + makes P visible; Ks now dead -> scratch

  unsigned char* scratch = (unsigned char*)Ks;   // [64 rows][1024 B = 64 c16]

  // attended = P V via swapped operands: lane holds D[m=16w+ln][nb + r]
  const int m = 16 * w + ln;
  for (int nc = 0; nc < 4; ++nc) {
    f32x4 acco[8];
    for (int j = 0; j < 8; ++j) acco[j] = (f32x4){0.f, 0.f, 0.f, 0.f};
    for (int ks = 0; ks < 2; ++ks) {
      bf16x8 pf = *(const bf16x8*)&P[m][ks * 32 + qd * 8];
      for (int j = 0; j < 8; ++j) {
        int row = nc * 128 + 16 * j + ln;
        bf16x8 vf = *(const bf16x8*)&Vs[row * 64 + (((ks * 4 + qd) ^ l7) * 8)];
        acco[j] = mfma16(vf, pf, acco[j]);
      }
    }
    for (int j = 0; j < 8; ++j) {
      int c16 = nc * 16 + 2 * j + (qd >> 1);
      bf16x4 pk;
      for (int r = 0; r < 4; ++r) pk[r] = (bf16_t)acco[j][r];
      *(bf16x4*)(scratch + m * 1024 + ((c16 ^ l7) * 16) + (qd & 1) * 8) = pk;
    }
  }
  __syncthreads();
  const long orow = (long)b * S + h * 64;
  for (int k = 0; k < 16; ++k) {
    int row = w * 16 + k;
    int c = lane;                                  // 64 chunks of 16 B
    bf16x8 v = *(const bf16x8*)(scratch + row * 1024 + ((c ^ (row & 7)) * 16));
    *(bf16x8*)&Att[(orow + row) * H + c * 8] = v;
  }
}

extern "C" void kernel_launch(void* const* d_in, const int* in_sizes, int n_in,
                              void* d_out, int out_size, void* d_ws, size_t ws_size,
                              hipStream_t stream)
{
  const float* x  = (const float*)d_in[0];
  const float* Wq = (const float*)d_in[1]; const float* bq = (const float*)d_in[2];
  const float* Wk = (const float*)d_in[3]; const float* bk = (const float*)d_in[4];
  const float* Wv = (const float*)d_in[5]; const float* bv = (const float*)d_in[6];
  const float* Wo = (const float*)d_in[7]; const float* bo = (const float*)d_in[8];
  const int* perm = (const int*)d_in[9];

  const int S = in_sizes[9];                 // 4096
  const int H = in_sizes[2];                 // 512
  const int B = in_sizes[0] / (S * H);       // 8
  const int M = B * S;                       // 32768

  size_t bufB = (size_t)M * H * sizeof(bf16_t);          // 32 MB
  size_t wB   = 4 * (size_t)H * H * sizeof(bf16_t);
  size_t need = 256 + 4 * bufB + wB + 4 * H * 2 + (size_t)S * 4;
  if (ws_size < need) return;

  char* p = (char*)d_ws;  p += 256;
  bf16_t* Xp = (bf16_t*)p;  p += bufB;        // aliased as Att after QKV GEMM
  bf16_t* Qp = (bf16_t*)p;  p += bufB;
  bf16_t* Kp = (bf16_t*)p;  p += bufB;
  bf16_t* Vt = (bf16_t*)p;  p += bufB;        // V^T: [b][head][chan][tok]
  bf16_t* Wb = (bf16_t*)p;  p += wB;
  bf16_t* bb = (bf16_t*)p;  p += 4 * H * 2;
  int* invp  = (int*)p;
  bf16_t* Att = Xp;

  invperm_kernel<<<(S + 255) / 256, 256, 0, stream>>>(perm, invp, S);
  convert_x_kernel<<<(M * H) / 2048, 256, 0, stream>>>(x, Xp, perm, S, H);
  dim3 gw((H * H) / 2048 + 1, 1, 4);
  convert_w_kernel<<<gw, 256, 0, stream>>>(Wq, bq, Wk, bk, Wv, bv, Wo, bo,
                                           Wb, bb, H);

  dim3 g1(M / 256, H / 256, 3);
  gemm_qkv_kernel<<<g1, 512, 0, stream>>>(Xp, Wb, bb, Qp, Kp, Vt, S, H);

  dim3 g2(B * (S / 64));
  attn_kernel<<<g2, 256, 0, stream>>>(Qp, Kp, Vt, Att, S, H);

  dim3 g3(M / 256, H / 256, 1);
  gemm_o_kernel<<<g3, 512, 0, stream>>>(Att, Wb, bb, (float*)d_out, invp, S, H);
}

// Round 6
// 248.395 us; speedup vs baseline: 1.1428x; 1.0304x over previous
//
#include <hip/hip_runtime.h>
#include <hip/hip_bf16.h>

typedef __bf16 bf16_t;
typedef __attribute__((ext_vector_type(8))) __bf16 bf16x8;
typedef __attribute__((ext_vector_type(4))) __bf16 bf16x4;
typedef __attribute__((ext_vector_type(4))) float f32x4;

static __device__ __forceinline__ f32x4 mfma16(bf16x8 a, bf16x8 b, f32x4 c) {
  return __builtin_amdgcn_mfma_f32_16x16x32_bf16(a, b, c, 0, 0, 0);
}

// async global->LDS, 16 B per lane. LDS dest is wave-uniform base + lane*16.
static __device__ __forceinline__ void async16(const void* g, void* l) {
  __builtin_amdgcn_global_load_lds(
      (const __attribute__((address_space(1))) void*)g,
      (__attribute__((address_space(3))) void*)l, 16, 0, 0);
}

static __device__ __forceinline__ bf16x8 load8f(const float* __restrict__ fp) {
  float4 a = *(const float4*)fp;
  float4 b = *(const float4*)(fp + 4);
  bf16x8 r;
  r[0] = (bf16_t)a.x; r[1] = (bf16_t)a.y; r[2] = (bf16_t)a.z; r[3] = (bf16_t)a.w;
  r[4] = (bf16_t)b.x; r[5] = (bf16_t)b.y; r[6] = (bf16_t)b.z; r[7] = (bf16_t)b.w;
  return r;
}

__global__ void invperm_kernel(const int* __restrict__ perm, int* __restrict__ invp, int S) {
  int i = blockIdx.x * 256 + threadIdx.x;
  if (i < S) invp[perm[i]] = i;
}

// x -> bf16, pre-applying the permutation: Xp[b*S+i] = (bf16) x[b*S+perm[i]]
__global__ __launch_bounds__(256) void convert_x_kernel(
    const float* __restrict__ x, bf16_t* __restrict__ Xp,
    const int* __restrict__ perm, int S, int H)
{
  int m = blockIdx.x * 4 + (threadIdx.x >> 6);
  int c = (threadIdx.x & 63) * 8;
  int b = m / S, i = m - b * S;
  long src = ((long)b * S + perm[i]) * H + c;
  *(bf16x8*)&Xp[(long)m * H + c] = load8f(x + src);
}

__global__ __launch_bounds__(256) void convert_w_kernel(
    const float* Wq, const float* bq, const float* Wk, const float* bk,
    const float* Wv, const float* bv, const float* Wo, const float* bo,
    bf16_t* __restrict__ Wb, bf16_t* __restrict__ bb, int H)
{
  const int z = blockIdx.z;
  const float* W  = (z == 0) ? Wq : (z == 1) ? Wk : (z == 2) ? Wv : Wo;
  const float* bi = (z == 0) ? bq : (z == 1) ? bk : (z == 2) ? bv : bo;
  bf16_t* dst = Wb + (long)z * H * H;
  int nwb = (H * H) / 2048;
  if ((int)blockIdx.x < nwb) {
    long e = (long)blockIdx.x * 2048 + threadIdx.x * 8;
    *(bf16x8*)&dst[e] = load8f(W + e);
  } else {
    int e = threadIdx.x * 8;
    if (e < H) *(bf16x8*)&bb[z * H + e] = load8f(bi + e);
  }
}

// ---------------------------------------------------------------------------
// GEMM core: r3's 4-phase/K-tile counted-vmcnt pipeline + r5's coalesced
// LDS-transpose epilogues. r6: block indices (bxi, byi) are passed in so the
// callers can apply an XCD-affinity remap (blocks sharing an A-panel land on
// the same XCD's L2 -> FETCH_SIZE drops toward the 34 MB ideal).
// BM=BN=256, BK=64, 512 threads = 8 waves (2M x 4N).
// MODE 0: bf16 C tile, row-major out (Q/K)
// MODE 1: f32 C tile (final out)
// MODE 2: writes V^T as [b][head][chan][tok]
// GATHER: A row m is gathered from row b*S + invp[m%S]
// ---------------------------------------------------------------------------
template<int MODE, bool GATHER>
__device__ __forceinline__ void gemm_core(
    unsigned char* __restrict__ smem,   // 128 KB
    int bxi, int byi,
    const bf16_t* __restrict__ A, const bf16_t* __restrict__ W,
    const bf16_t* __restrict__ bias, void* __restrict__ C,
    const int* __restrict__ invp, int N, int K, int S)
{
  bf16_t (*At)[64] = (bf16_t(*)[64])smem;             // [512][64]
  bf16_t (*Bt)[64] = (bf16_t(*)[64])(smem + 65536);   // [512][64]

  const int bm = bxi * 256, bn = byi * 256;
  const int tid = threadIdx.x, lane = tid & 63, w = tid >> 6;   // 8 waves
  const int qd = lane >> 4, ln = lane & 15, l7 = ln & 7;
  const int wm = w & 1, wn = w >> 1;            // 2M x 4N wave grid
  const int srow = lane >> 3;                   // 0..7 (row&7 of staged row)
  const int scol = ((lane & 7) ^ srow) * 8;     // swizzled global fetch chunk

  int ga[2][2], gb[2][2];
#pragma unroll
  for (int u = 0; u < 2; ++u) {
    int ix = w + 8 * u;                         // 0..15
    ga[0][u] = (ix & 7) + ((ix >> 3) << 4);
    ga[1][u] = ga[0][u] + 8;
    gb[0][u] = (ix & 3) + ((ix >> 2) << 3);
    gb[1][u] = gb[0][u] + 4;
  }
  long aoff[2][2], woff[2][2];
#pragma unroll
  for (int h = 0; h < 2; ++h)
#pragma unroll
    for (int u = 0; u < 2; ++u) {
      int mg = bm + ga[h][u] * 8 + srow;
      if (GATHER) { int b_ = mg / S; aoff[h][u] = ((long)b_ * S + invp[mg - b_ * S]) * K + scol; }
      else        { aoff[h][u] = (long)mg * K + scol; }
      woff[h][u] = (long)(bn + gb[h][u] * 8 + srow) * K + scol;
    }

  f32x4 acc[2][2][4][2];
#pragma unroll
  for (int a = 0; a < 2; ++a)
#pragma unroll
    for (int b = 0; b < 2; ++b)
#pragma unroll
      for (int i = 0; i < 4; ++i)
#pragma unroll
        for (int j = 0; j < 2; ++j)
          acc[a][b][i][j] = (f32x4){0.f, 0.f, 0.f, 0.f};

  bf16x8 af[4][2], bfr[2][2];
  const int NT = K >> 6;                         // 8 K-tiles for K=512

#define LOAD_A(RH)                                                            \
  _Pragma("unroll") for (int i = 0; i < 4; ++i)                               \
  _Pragma("unroll") for (int ks = 0; ks < 2; ++ks)                            \
    af[i][ks] = *(const bf16x8*)&At[sb + wm * 128 + (RH) * 64 + 16 * i + ln]  \
                                   [((ks * 4 + qd) ^ l7) * 8];
#define LOAD_B(CH)                                                            \
  _Pragma("unroll") for (int j = 0; j < 2; ++j)                               \
  _Pragma("unroll") for (int ks = 0; ks < 2; ++ks)                            \
    bfr[j][ks] = *(const bf16x8*)&Bt[sb + wn * 64 + (CH) * 32 + 16 * j + ln]  \
                                    [((ks * 4 + qd) ^ l7) * 8];
#define STAGE_A(HH)                                                           \
  if (st) {                                                                   \
    async16(&A[aoff[HH][0] + k2], &At[so + ga[HH][0] * 8][0]);                \
    async16(&A[aoff[HH][1] + k2], &At[so + ga[HH][1] * 8][0]);                \
  }
#define STAGE_B(CH)                                                           \
  if (st) {                                                                   \
    async16(&W[woff[CH][0] + k2], &Bt[so + gb[CH][0] * 8][0]);                \
    async16(&W[woff[CH][1] + k2], &Bt[so + gb[CH][1] * 8][0]);                \
  }
#define MFMA_Q(RH, CH)                                                        \
  __builtin_amdgcn_s_setprio(1);                                              \
  _Pragma("unroll") for (int i = 0; i < 4; ++i)                               \
  _Pragma("unroll") for (int j = 0; j < 2; ++j)                               \
  _Pragma("unroll") for (int ks = 0; ks < 2; ++ks) {                          \
    if (MODE == 2) acc[RH][CH][i][j] = mfma16(af[i][ks], bfr[j][ks], acc[RH][CH][i][j]); \
    else           acc[RH][CH][i][j] = mfma16(bfr[j][ks], af[i][ks], acc[RH][CH][i][j]); \
  }                                                                           \
  __builtin_amdgcn_s_setprio(0);
#define GATE2 asm volatile("s_waitcnt vmcnt(2)" ::: "memory")
#define GATE0 asm volatile("s_waitcnt vmcnt(0)" ::: "memory")
#define PH_MID                                                                \
  __builtin_amdgcn_s_barrier();                                               \
  asm volatile("s_waitcnt lgkmcnt(0)" ::: "memory");
#define PH_END __builtin_amdgcn_s_barrier();

  // prologue: stage tile 0 into slot 0 in deadline order A0,B0,B1,A1
  async16(&A[aoff[0][0]], &At[ga[0][0] * 8][0]);
  async16(&A[aoff[0][1]], &At[ga[0][1] * 8][0]);
  async16(&W[woff[0][0]], &Bt[gb[0][0] * 8][0]);
  async16(&W[woff[0][1]], &Bt[gb[0][1] * 8][0]);
  async16(&W[woff[1][0]], &Bt[gb[1][0] * 8][0]);
  async16(&W[woff[1][1]], &Bt[gb[1][1] * 8][0]);
  async16(&A[aoff[1][0]], &At[ga[1][0] * 8][0]);
  async16(&A[aoff[1][1]], &At[ga[1][1] * 8][0]);
  GATE2;
  __builtin_amdgcn_s_barrier();

  for (int kt = 0; kt < NT; ++kt) {
    const int sb = (kt & 1) << 8;          // compute-slot row base
    const int so = ((kt + 1) & 1) << 8;    // stage-slot row base
    const long k2 = (long)(kt + 1) << 6;
    const bool st = (kt + 1 < NT);

    // ---- phase 1: (rh=0, ch=0) ----
    GATE2;
    LOAD_A(0)
    LOAD_B(0)
    STAGE_A(0)
    PH_MID
    MFMA_Q(0, 0)
    PH_END
    // ---- phase 2: (rh=0, ch=1) ----
    if (st) { GATE2; } else { GATE0; }     // last tile: drain once here
    LOAD_B(1)
    STAGE_B(0)
    PH_MID
    MFMA_Q(0, 1)
    PH_END
    // ---- phase 3: (rh=1, ch=1) ----
    if (st) { GATE2; }
    LOAD_A(1)
    STAGE_B(1)
    PH_MID
    MFMA_Q(1, 1)
    PH_END
    // ---- phase 4: (rh=1, ch=0) ----
    if (st) { GATE2; }
    LOAD_B(0)
    STAGE_A(1)
    PH_MID
    MFMA_Q(1, 0)
    PH_END
  }

#undef LOAD_A
#undef LOAD_B
#undef STAGE_A
#undef STAGE_B
#undef MFMA_Q
#undef GATE2
#undef GATE0
#undef PH_MID
#undef PH_END

  // ---- coalesced epilogues via 16B-swizzled LDS transpose scratch ----
  if (MODE == 0) {
#pragma unroll
    for (int rh = 0; rh < 2; ++rh)
#pragma unroll
      for (int ch = 0; ch < 2; ++ch)
#pragma unroll
        for (int j = 0; j < 2; ++j) {
          bf16x4 b4 = *(const bf16x4*)&bias[bn + wn * 64 + ch * 32 + 16 * j + 4 * qd];
          int c16 = wn * 8 + ch * 4 + 2 * j + (qd >> 1);
#pragma unroll
          for (int i = 0; i < 4; ++i) {
            int m = wm * 128 + rh * 64 + 16 * i + ln;
            bf16x4 pk;
#pragma unroll
            for (int r = 0; r < 4; ++r) pk[r] = (bf16_t)(acc[rh][ch][i][j][r] + (float)b4[r]);
            *(bf16x4*)(smem + m * 512 + ((c16 ^ l7) * 16) + (qd & 1) * 8) = pk;
          }
        }
    __syncthreads();
#pragma unroll
    for (int k = 0; k < 16; ++k) {
      int row = w * 32 + 2 * k + (lane >> 5);
      int c = lane & 31;
      bf16x8 v = *(const bf16x8*)(smem + row * 512 + ((c ^ (row & 7)) * 16));
      *(bf16x8*)&((bf16_t*)C)[(long)(bm + row) * N + bn + c * 8] = v;
    }
  } else if (MODE == 1) {
#pragma unroll
    for (int rh = 0; rh < 2; ++rh) {
      if (rh) __syncthreads();
#pragma unroll
      for (int ch = 0; ch < 2; ++ch)
#pragma unroll
        for (int j = 0; j < 2; ++j) {
          bf16x4 b4 = *(const bf16x4*)&bias[bn + wn * 64 + ch * 32 + 16 * j + 4 * qd];
          int c16 = wn * 16 + ch * 8 + 4 * j + qd;
#pragma unroll
          for (int i = 0; i < 4; ++i) {
            int hrow = wm * 64 + 16 * i + ln;
            float4 pk = {acc[rh][ch][i][j][0] + (float)b4[0], acc[rh][ch][i][j][1] + (float)b4[1],
                         acc[rh][ch][i][j][2] + (float)b4[2], acc[rh][ch][i][j][3] + (float)b4[3]};
            *(float4*)(smem + hrow * 1024 + ((c16 ^ l7) * 16)) = pk;
          }
        }
      __syncthreads();
#pragma unroll
      for (int k = 0; k < 16; ++k) {
        int hrow = w + 8 * k;
        float4 v = *(const float4*)(smem + hrow * 1024 + (((lane) ^ (hrow & 7)) * 16));
        int gm = bm + (hrow >> 6) * 128 + rh * 64 + (hrow & 63);
        *(float4*)&((float*)C)[(long)gm * N + bn + lane * 4] = v;
      }
    }
  } else {
    const int heads = S >> 6;
    const int b_ = bm / S;
    const int h0 = (bm - b_ * S) >> 6;          // head base of this block
#pragma unroll
    for (int rh = 0; rh < 2; ++rh)
#pragma unroll
      for (int ch = 0; ch < 2; ++ch)
#pragma unroll
        for (int j = 0; j < 2; ++j) {
          int n = wn * 64 + ch * 32 + 16 * j + ln;
          float bv = (float)bias[bn + n];
#pragma unroll
          for (int i = 0; i < 4; ++i) {
            int c16 = wm * 16 + rh * 8 + 2 * i + (qd >> 1);
            bf16x4 pk;
#pragma unroll
            for (int r = 0; r < 4; ++r) pk[r] = (bf16_t)(acc[rh][ch][i][j][r] + bv);
            *(bf16x4*)(smem + n * 512 + ((c16 ^ l7) * 16) + (qd & 1) * 8) = pk;
          }
        }
    __syncthreads();
#pragma unroll
    for (int k = 0; k < 16; ++k) {
      int h4 = k >> 2;                            // local head (m block)
      int n = (w + 8 * (k & 3)) * 8 + (lane >> 3);
      int tc = lane & 7;                          // 16B tok-chunk
      bf16x8 v = *(const bf16x8*)(smem + n * 512 + (((h4 * 8 + tc) ^ (n & 7)) * 16));
      *(bf16x8*)&((bf16_t*)C)[(((long)(b_ * heads + h0 + h4) * N + bn + n) << 6) + tc * 8] = v;
    }
  }
}

// XCD-affinity remap: flat id -> (bxi, byi, z) so that all blocks sharing an
// A-panel (same bxi, varying byi/z) have ids congruent mod 8 -> same XCD L2.
// Bijective when gridDim.x % 8 == 0 (128 here); identity fallback otherwise.
__global__ __launch_bounds__(512, 2) void gemm_qkv_kernel(
    const bf16_t* __restrict__ Xp, const bf16_t* __restrict__ Wb,
    const bf16_t* __restrict__ bb,
    bf16_t* __restrict__ Qp, bf16_t* __restrict__ Kp, bf16_t* __restrict__ Vt,
    int S, int H)
{
  __shared__ __align__(16) unsigned char smem[131072];
  int bxi = blockIdx.x, byi = blockIdx.y, z = blockIdx.z;
  const int nx = gridDim.x;
  if ((nx & 7) == 0) {
    int id = blockIdx.x + nx * (blockIdx.y + gridDim.y * blockIdx.z);
    int cx = nx >> 3;                 // bm-range per XCD
    int xcd = id & 7, k = id >> 3;
    bxi = xcd * cx + (k % cx);
    int r = k / cx;                   // 0 .. 2*gridDim.y-1 ... (byi,z) rounds
    byi = r % gridDim.y;
    z = r / gridDim.y;
  }
  if (z < 2)
    gemm_core<0, false>(smem, bxi, byi, Xp, Wb + (long)z * H * H, bb + z * H,
                        z ? (void*)Kp : (void*)Qp, nullptr, H, H, S);
  else
    gemm_core<2, false>(smem, bxi, byi, Xp, Wb + 2L * H * H, bb + 2 * H, Vt,
                        nullptr, H, H, S);
}

__global__ __launch_bounds__(512, 2) void gemm_o_kernel(
    const bf16_t* __restrict__ Att, const bf16_t* __restrict__ Wb,
    const bf16_t* __restrict__ bb, float* __restrict__ C,
    const int* __restrict__ invp, int S, int H)
{
  __shared__ __align__(16) unsigned char smem[131072];
  int bxi = blockIdx.x, byi = blockIdx.y;
  const int nx = gridDim.x;
  if ((nx & 7) == 0) {
    int id = blockIdx.x + nx * blockIdx.y;
    int cx = nx >> 3;
    int xcd = id & 7, k = id >> 3;
    bxi = xcd * cx + (k % cx);
    byi = k / cx;
  }
  gemm_core<1, true>(smem, bxi, byi, Att, Wb + 3L * H * H, bb + 3 * H, C, invp, H, H, S);
}

// ---------------------------------------------------------------------------
// attn v2 (r6): 2 blocks/CU. LDS cut 137 -> 73 KB by chan-chunking K and V:
//   Ks[64][256] 32 KB (staged twice: chans 0-255, then 256-511; slab reused
//   as the output-transpose scratch after QK), Vs[256][64] 32 KB (V^T rows
//   0-255 then 256-511), P 9 KB.
// Raw s_barrier + explicit lgkmcnt(0)/vmcnt gates (NOT __syncthreads: its
// vmcnt(0) drain would kill the V0 overlap). Ledger (per thread issues):
//   K0(8) | fence | Q(16)+V0(8) | vmcnt(24) -> K0 landed | bar
//   QK0 | lgkm0 bar (all K0 reads done) | K1(8) | vmcnt(0) bar -> K1,V0 in
//   QK1, softmax, P | lgkm0 bar | PV0 -> scratch | lgkm0 bar (Vs reads done)
//   V1(8) | store half0 from scratch | vmcnt(0) bar -> V1 in | PV1 -> scratch
//   | lgkm0 bar | store half1.
// Exposed vmcnt(0) gates hide under the co-resident block (2/CU).
// Numerics identical to r5 (chan chunks are independent outputs; QK keeps
// the same t-order K-sum).
// ---------------------------------------------------------------------------
__global__ __launch_bounds__(256) void attn_kernel(
    const bf16_t* __restrict__ Qp, const bf16_t* __restrict__ Kp,
    const bf16_t* __restrict__ Vt, bf16_t* __restrict__ Att,
    int S, int H)
{
  const int heads = S >> 6;
  const int b = blockIdx.x / heads;
  const int h = blockIdx.x % heads;
  const long qkbase = ((long)b * S + h * 64) * H;
  const long vbase  = (long)(b * heads + h) * H * 64;

  const int tid = threadIdx.x, lane = tid & 63, w = tid >> 6;
  const int qd = lane >> 4, ln = lane & 15;
  const int l7 = ln & 7;

  __shared__ bf16_t Ks[64 * 256];   // 32 KB K chan-chunk; later out-scratch
  __shared__ bf16_t Vs[256 * 64];   // 32 KB V^T chan-chunk
  __shared__ bf16_t P[64][72];      // 9 KB softmax weights

  // stage K chunk0 (chans 0-255): 8 instr/thread, 1 wave-instr = 2 rows
  for (int u = 0; u < 8; ++u) {
    int row = 16 * w + 2 * u + (lane >> 5);
    int c = lane & 31;
    async16(&Kp[qkbase + (long)row * H + ((c ^ (row & 7)) * 8)],
            &Ks[(16 * w + 2 * u) * 256]);
  }
  asm volatile("" ::: "memory");     // pin K0 first in the vmcnt ledger
  // Q frags (16 global loads)
  bf16x8 qf[16];
  for (int t = 0; t < 16; ++t)
    qf[t] = *(const bf16x8*)&Qp[qkbase + (long)(16 * w + ln) * H + t * 32 + qd * 8];
  // stage V chunk0 (V^T rows 0-255): 8 instr/thread, 1 wave-instr = 8 rows
  for (int u = 0; u < 8; ++u) {
    int rowb = 64 * w + 8 * u;
    async16(&Vt[vbase + (long)(rowb + (lane >> 3)) * 64 +
                (((lane & 7) ^ ((lane >> 3) & 7)) * 8)],
            &Vs[rowb * 64]);
  }
  asm volatile("s_waitcnt vmcnt(24)" ::: "memory");   // K0 landed (Q+V0 fly)
  __builtin_amdgcn_s_barrier();

  // QK chunk0: chans 0-255 (t = 0..7)
  f32x4 accs[4];
  for (int j = 0; j < 4; ++j) accs[j] = (f32x4){0.f, 0.f, 0.f, 0.f};
  for (int t = 0; t < 8; ++t)
    for (int j = 0; j < 4; ++j) {
      bf16x8 kf = *(const bf16x8*)&Ks[(16 * j + ln) * 256 + (((t * 4 + qd) ^ l7) * 8)];
      accs[j] = mfma16(qf[t], kf, accs[j]);
    }
  asm volatile("s_waitcnt lgkmcnt(0)" ::: "memory");
  __builtin_amdgcn_s_barrier();       // all waves done reading K0
  // stage K chunk1 (chans 256-511) into the same slab
  for (int u = 0; u < 8; ++u) {
    int row = 16 * w + 2 * u + (lane >> 5);
    int c = lane & 31;
    async16(&Kp[qkbase + (long)row * H + 256 + ((c ^ (row & 7)) * 8)],
            &Ks[(16 * w + 2 * u) * 256]);
  }
  asm volatile("s_waitcnt vmcnt(0)" ::: "memory");    // K1 (and V0) landed
  __builtin_amdgcn_s_barrier();
  // QK chunk1: chans 256-511 (t = 8..15)
  for (int t = 8; t < 16; ++t)
    for (int j = 0; j < 4; ++j) {
      bf16x8 kf = *(const bf16x8*)&Ks[(16 * j + ln) * 256 + ((((t - 8) * 4 + qd) ^ l7) * 8)];
      accs[j] = mfma16(qf[t], kf, accs[j]);
    }

  // register softmax, normalized weights into P (LDS) — identical to r5
  const float rscale = rsqrtf((float)H);
  for (int r = 0; r < 4; ++r) {
    float s[4];
    for (int j = 0; j < 4; ++j) s[j] = accs[j][r] * rscale;
    float mx = fmaxf(fmaxf(s[0], s[1]), fmaxf(s[2], s[3]));
    mx = fmaxf(mx, __shfl_xor(mx, 1));
    mx = fmaxf(mx, __shfl_xor(mx, 2));
    mx = fmaxf(mx, __shfl_xor(mx, 4));
    mx = fmaxf(mx, __shfl_xor(mx, 8));
    float e[4], sum = 0.f;
    for (int j = 0; j < 4; ++j) {
      e[j] = (float)(bf16_t)__expf(s[j] - mx);
      sum += e[j];
    }
    sum += __shfl_xor(sum, 1);
    sum += __shfl_xor(sum, 2);
    sum += __shfl_xor(sum, 4);
    sum += __shfl_xor(sum, 8);
    float rs = 1.f / sum;
    for (int j = 0; j < 4; ++j)
      P[16 * w + qd * 4 + r][16 * j + ln] = (bf16_t)(e[j] * rs);
  }
  asm volatile("s_waitcnt lgkmcnt(0)" ::: "memory");
  __builtin_amdgcn_s_barrier();   // P visible; Ks dead -> scratch; Vs = V0

  unsigned char* scratch = (unsigned char*)Ks;   // [64 rows][512 B]
  const int m = 16 * w + ln;
  const long orow = (long)b * S + h * 64;

#pragma unroll
  for (int half = 0; half < 2; ++half) {
    // PV over this chan half: out chans half*256 + (nc*128 + 16j + 4qd + r)
    for (int nc = 0; nc < 2; ++nc) {
      f32x4 acco[8];
      for (int j = 0; j < 8; ++j) acco[j] = (f32x4){0.f, 0.f, 0.f, 0.f};
      for (int ks = 0; ks < 2; ++ks) {
        bf16x8 pf = *(const bf16x8*)&P[m][ks * 32 + qd * 8];
        for (int j = 0; j < 8; ++j) {
          int row = nc * 128 + 16 * j + ln;
          bf16x8 vf = *(const bf16x8*)&Vs[row * 64 + (((ks * 4 + qd) ^ l7) * 8)];
          acco[j] = mfma16(vf, pf, acco[j]);
        }
      }
      for (int j = 0; j < 8; ++j) {
        int c16 = nc * 16 + 2 * j + (qd >> 1);
        bf16x4 pk;
        for (int r = 0; r < 4; ++r) pk[r] = (bf16_t)acco[j][r];
        *(bf16x4*)(scratch + m * 512 + ((c16 ^ l7) * 16) + (qd & 1) * 8) = pk;
      }
    }
    asm volatile("s_waitcnt lgkmcnt(0)" ::: "memory");
    __builtin_amdgcn_s_barrier();     // Vs reads + scratch writes done, all waves
    if (half == 0) {
      // stage V chunk1 (V^T rows 256-511) while half0 stores run
      for (int u = 0; u < 8; ++u) {
        int rowb = 64 * w + 8 * u;
        async16(&Vt[vbase + (long)(256 + rowb + (lane >> 3)) * 64 +
                    (((lane & 7) ^ ((lane >> 3) & 7)) * 8)],
                &Vs[rowb * 64]);
      }
    }
    // store this half: contiguous 512 B runs per half-wave
    for (int k = 0; k < 8; ++k) {
      int row = 16 * w + 2 * k + (lane >> 5);
      int c = lane & 31;
      bf16x8 v = *(const bf16x8*)(scratch + row * 512 + ((c ^ (row & 7)) * 16));
      *(bf16x8*)&Att[(orow + row) * H + half * 256 + c * 8] = v;
    }
    if (half == 0) {
      asm volatile("s_waitcnt vmcnt(0)" ::: "memory");  // V1 landed
      __builtin_amdgcn_s_barrier();
    }
  }
}

extern "C" void kernel_launch(void* const* d_in, const int* in_sizes, int n_in,
                              void* d_out, int out_size, void* d_ws, size_t ws_size,
                              hipStream_t stream)
{
  const float* x  = (const float*)d_in[0];
  const float* Wq = (const float*)d_in[1]; const float* bq = (const float*)d_in[2];
  const float* Wk = (const float*)d_in[3]; const float* bk = (const float*)d_in[4];
  const float* Wv = (const float*)d_in[5]; const float* bv = (const float*)d_in[6];
  const float* Wo = (const float*)d_in[7]; const float* bo = (const float*)d_in[8];
  const int* perm = (const int*)d_in[9];

  const int S = in_sizes[9];                 // 4096
  const int H = in_sizes[2];                 // 512
  const int B = in_sizes[0] / (S * H);       // 8
  const int M = B * S;                       // 32768

  size_t bufB = (size_t)M * H * sizeof(bf16_t);          // 32 MB
  size_t wB   = 4 * (size_t)H * H * sizeof(bf16_t);
  size_t need = 256 + 4 * bufB + wB + 4 * H * 2 + (size_t)S * 4;
  if (ws_size < need) return;

  char* p = (char*)d_ws;  p += 256;
  bf16_t* Xp = (bf16_t*)p;  p += bufB;        // aliased as Att after QKV GEMM
  bf16_t* Qp = (bf16_t*)p;  p += bufB;
  bf16_t* Kp = (bf16_t*)p;  p += bufB;
  bf16_t* Vt = (bf16_t*)p;  p += bufB;        // V^T: [b][head][chan][tok]
  bf16_t* Wb = (bf16_t*)p;  p += wB;
  bf16_t* bb = (bf16_t*)p;  p += 4 * H * 2;
  int* invp  = (int*)p;
  bf16_t* Att = Xp;

  invperm_kernel<<<(S + 255) / 256, 256, 0, stream>>>(perm, invp, S);
  convert_x_kernel<<<(M * H) / 2048, 256, 0, stream>>>(x, Xp, perm, S, H);
  dim3 gw((H * H) / 2048 + 1, 1, 4);
  convert_w_kernel<<<gw, 256, 0, stream>>>(Wq, bq, Wk, bk, Wv, bv, Wo, bo,
                                           Wb, bb, H);

  dim3 g1(M / 256, H / 256, 3);
  gemm_qkv_kernel<<<g1, 512, 0, stream>>>(Xp, Wb, bb, Qp, Kp, Vt, S, H);

  dim3 g2(B * (S / 64));
  attn_kernel<<<g2, 256, 0, stream>>>(Qp, Kp, Vt, Att, S, H);

  dim3 g3(M / 256, H / 256, 1);
  gemm_o_kernel<<<g3, 512, 0, stream>>>(Att, Wb, bb, (float*)d_out, invp, S, H);
}

// Round 7
// 248.000 us; speedup vs baseline: 1.1446x; 1.0016x over previous
//
#include <hip/hip_runtime.h>
#include <hip/hip_bf16.h>

typedef __bf16 bf16_t;
typedef __attribute__((ext_vector_type(8))) __bf16 bf16x8;
typedef __attribute__((ext_vector_type(4))) __bf16 bf16x4;
typedef __attribute__((ext_vector_type(4))) float f32x4;

static __device__ __forceinline__ f32x4 mfma16(bf16x8 a, bf16x8 b, f32x4 c) {
  return __builtin_amdgcn_mfma_f32_16x16x32_bf16(a, b, c, 0, 0, 0);
}

// async global->LDS, 16 B per lane. LDS dest is wave-uniform base + lane*16.
static __device__ __forceinline__ void async16(const void* g, void* l) {
  __builtin_amdgcn_global_load_lds(
      (const __attribute__((address_space(1))) void*)g,
      (__attribute__((address_space(3))) void*)l, 16, 0, 0);
}

static __device__ __forceinline__ bf16x8 load8f(const float* __restrict__ fp) {
  float4 a = *(const float4*)fp;
  float4 b = *(const float4*)(fp + 4);
  bf16x8 r;
  r[0] = (bf16_t)a.x; r[1] = (bf16_t)a.y; r[2] = (bf16_t)a.z; r[3] = (bf16_t)a.w;
  r[4] = (bf16_t)b.x; r[5] = (bf16_t)b.y; r[6] = (bf16_t)b.z; r[7] = (bf16_t)b.w;
  return r;
}

__global__ void invperm_kernel(const int* __restrict__ perm, int* __restrict__ invp, int S) {
  int i = blockIdx.x * 256 + threadIdx.x;
  if (i < S) invp[perm[i]] = i;
}

// x -> bf16, pre-applying the permutation: Xp[b*S+i] = (bf16) x[b*S+perm[i]]
__global__ __launch_bounds__(256) void convert_x_kernel(
    const float* __restrict__ x, bf16_t* __restrict__ Xp,
    const int* __restrict__ perm, int S, int H)
{
  int m = blockIdx.x * 4 + (threadIdx.x >> 6);
  int c = (threadIdx.x & 63) * 8;
  int b = m / S, i = m - b * S;
  long src = ((long)b * S + perm[i]) * H + c;
  *(bf16x8*)&Xp[(long)m * H + c] = load8f(x + src);
}

__global__ __launch_bounds__(256) void convert_w_kernel(
    const float* Wq, const float* bq, const float* Wk, const float* bk,
    const float* Wv, const float* bv, const float* Wo, const float* bo,
    bf16_t* __restrict__ Wb, bf16_t* __restrict__ bb, int H)
{
  const int z = blockIdx.z;
  const float* W  = (z == 0) ? Wq : (z == 1) ? Wk : (z == 2) ? Wv : Wo;
  const float* bi = (z == 0) ? bq : (z == 1) ? bk : (z == 2) ? bv : bo;
  bf16_t* dst = Wb + (long)z * H * H;
  int nwb = (H * H) / 2048;
  if ((int)blockIdx.x < nwb) {
    long e = (long)blockIdx.x * 2048 + threadIdx.x * 8;
    *(bf16x8*)&dst[e] = load8f(W + e);
  } else {
    int e = threadIdx.x * 8;
    if (e < H) *(bf16x8*)&bb[z * H + e] = load8f(bi + e);
  }
}

// ---------------------------------------------------------------------------
// GEMM core: r3's 4-phase/K-tile counted-vmcnt pipeline + r5's coalesced
// LDS-transpose epilogues. r7: XCD remap REVERTED (r6 measured: FETCH_SIZE
// byte-identical -> zero L2 benefit; -36% wall time. Default mapping already
// gives each XCD a 4 MB A-footprint; the permutation had nothing to win).
// BM=BN=256, BK=64, 512 threads = 8 waves (2M x 4N).
// MODE 0: bf16 C tile, row-major out (Q/K)
// MODE 1: f32 C tile (final out)
// MODE 2: writes V^T as [b][head][chan][tok]
// GATHER: A row m is gathered from row b*S + invp[m%S]
// ---------------------------------------------------------------------------
template<int MODE, bool GATHER>
__device__ __forceinline__ void gemm_core(
    unsigned char* __restrict__ smem,   // 128 KB
    const bf16_t* __restrict__ A, const bf16_t* __restrict__ W,
    const bf16_t* __restrict__ bias, void* __restrict__ C,
    const int* __restrict__ invp, int N, int K, int S)
{
  bf16_t (*At)[64] = (bf16_t(*)[64])smem;             // [512][64]
  bf16_t (*Bt)[64] = (bf16_t(*)[64])(smem + 65536);   // [512][64]

  const int bm = blockIdx.x * 256, bn = blockIdx.y * 256;
  const int tid = threadIdx.x, lane = tid & 63, w = tid >> 6;   // 8 waves
  const int qd = lane >> 4, ln = lane & 15, l7 = ln & 7;
  const int wm = w & 1, wn = w >> 1;            // 2M x 4N wave grid
  const int srow = lane >> 3;                   // 0..7 (row&7 of staged row)
  const int scol = ((lane & 7) ^ srow) * 8;     // swizzled global fetch chunk

  int ga[2][2], gb[2][2];
#pragma unroll
  for (int u = 0; u < 2; ++u) {
    int ix = w + 8 * u;                         // 0..15
    ga[0][u] = (ix & 7) + ((ix >> 3) << 4);
    ga[1][u] = ga[0][u] + 8;
    gb[0][u] = (ix & 3) + ((ix >> 2) << 3);
    gb[1][u] = gb[0][u] + 4;
  }
  long aoff[2][2], woff[2][2];
#pragma unroll
  for (int h = 0; h < 2; ++h)
#pragma unroll
    for (int u = 0; u < 2; ++u) {
      int mg = bm + ga[h][u] * 8 + srow;
      if (GATHER) { int b_ = mg / S; aoff[h][u] = ((long)b_ * S + invp[mg - b_ * S]) * K + scol; }
      else        { aoff[h][u] = (long)mg * K + scol; }
      woff[h][u] = (long)(bn + gb[h][u] * 8 + srow) * K + scol;
    }

  f32x4 acc[2][2][4][2];
#pragma unroll
  for (int a = 0; a < 2; ++a)
#pragma unroll
    for (int b = 0; b < 2; ++b)
#pragma unroll
      for (int i = 0; i < 4; ++i)
#pragma unroll
        for (int j = 0; j < 2; ++j)
          acc[a][b][i][j] = (f32x4){0.f, 0.f, 0.f, 0.f};

  bf16x8 af[4][2], bfr[2][2];
  const int NT = K >> 6;                         // 8 K-tiles for K=512

#define LOAD_A(RH)                                                            \
  _Pragma("unroll") for (int i = 0; i < 4; ++i)                               \
  _Pragma("unroll") for (int ks = 0; ks < 2; ++ks)                            \
    af[i][ks] = *(const bf16x8*)&At[sb + wm * 128 + (RH) * 64 + 16 * i + ln]  \
                                   [((ks * 4 + qd) ^ l7) * 8];
#define LOAD_B(CH)                                                            \
  _Pragma("unroll") for (int j = 0; j < 2; ++j)                               \
  _Pragma("unroll") for (int ks = 0; ks < 2; ++ks)                            \
    bfr[j][ks] = *(const bf16x8*)&Bt[sb + wn * 64 + (CH) * 32 + 16 * j + ln]  \
                                    [((ks * 4 + qd) ^ l7) * 8];
#define STAGE_A(HH)                                                           \
  if (st) {                                                                   \
    async16(&A[aoff[HH][0] + k2], &At[so + ga[HH][0] * 8][0]);                \
    async16(&A[aoff[HH][1] + k2], &At[so + ga[HH][1] * 8][0]);                \
  }
#define STAGE_B(CH)                                                           \
  if (st) {                                                                   \
    async16(&W[woff[CH][0] + k2], &Bt[so + gb[CH][0] * 8][0]);                \
    async16(&W[woff[CH][1] + k2], &Bt[so + gb[CH][1] * 8][0]);                \
  }
#define MFMA_Q(RH, CH)                                                        \
  __builtin_amdgcn_s_setprio(1);                                              \
  _Pragma("unroll") for (int i = 0; i < 4; ++i)                               \
  _Pragma("unroll") for (int j = 0; j < 2; ++j)                               \
  _Pragma("unroll") for (int ks = 0; ks < 2; ++ks) {                          \
    if (MODE == 2) acc[RH][CH][i][j] = mfma16(af[i][ks], bfr[j][ks], acc[RH][CH][i][j]); \
    else           acc[RH][CH][i][j] = mfma16(bfr[j][ks], af[i][ks], acc[RH][CH][i][j]); \
  }                                                                           \
  __builtin_amdgcn_s_setprio(0);
#define GATE2 asm volatile("s_waitcnt vmcnt(2)" ::: "memory")
#define GATE0 asm volatile("s_waitcnt vmcnt(0)" ::: "memory")
#define PH_MID                                                                \
  __builtin_amdgcn_s_barrier();                                               \
  asm volatile("s_waitcnt lgkmcnt(0)" ::: "memory");
#define PH_END __builtin_amdgcn_s_barrier();

  // prologue: stage tile 0 into slot 0 in deadline order A0,B0,B1,A1
  async16(&A[aoff[0][0]], &At[ga[0][0] * 8][0]);
  async16(&A[aoff[0][1]], &At[ga[0][1] * 8][0]);
  async16(&W[woff[0][0]], &Bt[gb[0][0] * 8][0]);
  async16(&W[woff[0][1]], &Bt[gb[0][1] * 8][0]);
  async16(&W[woff[1][0]], &Bt[gb[1][0] * 8][0]);
  async16(&W[woff[1][1]], &Bt[gb[1][1] * 8][0]);
  async16(&A[aoff[1][0]], &At[ga[1][0] * 8][0]);
  async16(&A[aoff[1][1]], &At[ga[1][1] * 8][0]);
  GATE2;
  __builtin_amdgcn_s_barrier();

  for (int kt = 0; kt < NT; ++kt) {
    const int sb = (kt & 1) << 8;          // compute-slot row base
    const int so = ((kt + 1) & 1) << 8;    // stage-slot row base
    const long k2 = (long)(kt + 1) << 6;
    const bool st = (kt + 1 < NT);

    // ---- phase 1: (rh=0, ch=0) ----
    GATE2;
    LOAD_A(0)
    LOAD_B(0)
    STAGE_A(0)
    PH_MID
    MFMA_Q(0, 0)
    PH_END
    // ---- phase 2: (rh=0, ch=1) ----
    if (st) { GATE2; } else { GATE0; }     // last tile: drain once here
    LOAD_B(1)
    STAGE_B(0)
    PH_MID
    MFMA_Q(0, 1)
    PH_END
    // ---- phase 3: (rh=1, ch=1) ----
    if (st) { GATE2; }
    LOAD_A(1)
    STAGE_B(1)
    PH_MID
    MFMA_Q(1, 1)
    PH_END
    // ---- phase 4: (rh=1, ch=0) ----
    if (st) { GATE2; }
    LOAD_B(0)
    STAGE_A(1)
    PH_MID
    MFMA_Q(1, 0)
    PH_END
  }

#undef LOAD_A
#undef LOAD_B
#undef STAGE_A
#undef STAGE_B
#undef MFMA_Q
#undef GATE2
#undef GATE0
#undef PH_MID
#undef PH_END

  // ---- coalesced epilogues via 16B-swizzled LDS transpose scratch ----
  if (MODE == 0) {
#pragma unroll
    for (int rh = 0; rh < 2; ++rh)
#pragma unroll
      for (int ch = 0; ch < 2; ++ch)
#pragma unroll
        for (int j = 0; j < 2; ++j) {
          bf16x4 b4 = *(const bf16x4*)&bias[bn + wn * 64 + ch * 32 + 16 * j + 4 * qd];
          int c16 = wn * 8 + ch * 4 + 2 * j + (qd >> 1);
#pragma unroll
          for (int i = 0; i < 4; ++i) {
            int m = wm * 128 + rh * 64 + 16 * i + ln;
            bf16x4 pk;
#pragma unroll
            for (int r = 0; r < 4; ++r) pk[r] = (bf16_t)(acc[rh][ch][i][j][r] + (float)b4[r]);
            *(bf16x4*)(smem + m * 512 + ((c16 ^ l7) * 16) + (qd & 1) * 8) = pk;
          }
        }
    __syncthreads();
#pragma unroll
    for (int k = 0; k < 16; ++k) {
      int row = w * 32 + 2 * k + (lane >> 5);
      int c = lane & 31;
      bf16x8 v = *(const bf16x8*)(smem + row * 512 + ((c ^ (row & 7)) * 16));
      *(bf16x8*)&((bf16_t*)C)[(long)(bm + row) * N + bn + c * 8] = v;
    }
  } else if (MODE == 1) {
#pragma unroll
    for (int rh = 0; rh < 2; ++rh) {
      if (rh) __syncthreads();
#pragma unroll
      for (int ch = 0; ch < 2; ++ch)
#pragma unroll
        for (int j = 0; j < 2; ++j) {
          bf16x4 b4 = *(const bf16x4*)&bias[bn + wn * 64 + ch * 32 + 16 * j + 4 * qd];
          int c16 = wn * 16 + ch * 8 + 4 * j + qd;
#pragma unroll
          for (int i = 0; i < 4; ++i) {
            int hrow = wm * 64 + 16 * i + ln;
            float4 pk = {acc[rh][ch][i][j][0] + (float)b4[0], acc[rh][ch][i][j][1] + (float)b4[1],
                         acc[rh][ch][i][j][2] + (float)b4[2], acc[rh][ch][i][j][3] + (float)b4[3]};
            *(float4*)(smem + hrow * 1024 + ((c16 ^ l7) * 16)) = pk;
          }
        }
      __syncthreads();
#pragma unroll
      for (int k = 0; k < 16; ++k) {
        int hrow = w + 8 * k;
        float4 v = *(const float4*)(smem + hrow * 1024 + (((lane) ^ (hrow & 7)) * 16));
        int gm = bm + (hrow >> 6) * 128 + rh * 64 + (hrow & 63);
        *(float4*)&((float*)C)[(long)gm * N + bn + lane * 4] = v;
      }
    }
  } else {
    const int heads = S >> 6;
    const int b_ = bm / S;
    const int h0 = (bm - b_ * S) >> 6;          // head base of this block
#pragma unroll
    for (int rh = 0; rh < 2; ++rh)
#pragma unroll
      for (int ch = 0; ch < 2; ++ch)
#pragma unroll
        for (int j = 0; j < 2; ++j) {
          int n = wn * 64 + ch * 32 + 16 * j + ln;
          float bv = (float)bias[bn + n];
#pragma unroll
          for (int i = 0; i < 4; ++i) {
            int c16 = wm * 16 + rh * 8 + 2 * i + (qd >> 1);
            bf16x4 pk;
#pragma unroll
            for (int r = 0; r < 4; ++r) pk[r] = (bf16_t)(acc[rh][ch][i][j][r] + bv);
            *(bf16x4*)(smem + n * 512 + ((c16 ^ l7) * 16) + (qd & 1) * 8) = pk;
          }
        }
    __syncthreads();
#pragma unroll
    for (int k = 0; k < 16; ++k) {
      int h4 = k >> 2;                            // local head (m block)
      int n = (w + 8 * (k & 3)) * 8 + (lane >> 3);
      int tc = lane & 7;                          // 16B tok-chunk
      bf16x8 v = *(const bf16x8*)(smem + n * 512 + (((h4 * 8 + tc) ^ (n & 7)) * 16));
      *(bf16x8*)&((bf16_t*)C)[(((long)(b_ * heads + h0 + h4) * N + bn + n) << 6) + tc * 8] = v;
    }
  }
}

__global__ __launch_bounds__(512, 2) void gemm_qkv_kernel(
    const bf16_t* __restrict__ Xp, const bf16_t* __restrict__ Wb,
    const bf16_t* __restrict__ bb,
    bf16_t* __restrict__ Qp, bf16_t* __restrict__ Kp, bf16_t* __restrict__ Vt,
    int S, int H)
{
  __shared__ __align__(16) unsigned char smem[131072];
  const int z = blockIdx.z;
  if (z < 2)
    gemm_core<0, false>(smem, Xp, Wb + (long)z * H * H, bb + z * H,
                        z ? (void*)Kp : (void*)Qp, nullptr, H, H, S);
  else
    gemm_core<2, false>(smem, Xp, Wb + 2L * H * H, bb + 2 * H, Vt, nullptr, H, H, S);
}

__global__ __launch_bounds__(512, 2) void gemm_o_kernel(
    const bf16_t* __restrict__ Att, const bf16_t* __restrict__ Wb,
    const bf16_t* __restrict__ bb, float* __restrict__ C,
    const int* __restrict__ invp, int S, int H)
{
  __shared__ __align__(16) unsigned char smem[131072];
  gemm_core<1, true>(smem, Att, Wb + 3L * H * H, bb + 3 * H, C, invp, H, H, S);
}

// ---------------------------------------------------------------------------
// attn v2 (r6, kept): 2 blocks/CU. LDS 73 KB via chan-chunked K and V.
// Raw s_barrier + explicit lgkmcnt(0)/vmcnt gates; exposed vmcnt(0) gates
// hide under the co-resident block. Measured (r6 vs r5 totals): ~-33us
// across attn + rest.
// ---------------------------------------------------------------------------
__global__ __launch_bounds__(256) void attn_kernel(
    const bf16_t* __restrict__ Qp, const bf16_t* __restrict__ Kp,
    const bf16_t* __restrict__ Vt, bf16_t* __restrict__ Att,
    int S, int H)
{
  const int heads = S >> 6;
  const int b = blockIdx.x / heads;
  const int h = blockIdx.x % heads;
  const long qkbase = ((long)b * S + h * 64) * H;
  const long vbase  = (long)(b * heads + h) * H * 64;

  const int tid = threadIdx.x, lane = tid & 63, w = tid >> 6;
  const int qd = lane >> 4, ln = lane & 15;
  const int l7 = ln & 7;

  __shared__ bf16_t Ks[64 * 256];   // 32 KB K chan-chunk; later out-scratch
  __shared__ bf16_t Vs[256 * 64];   // 32 KB V^T chan-chunk
  __shared__ bf16_t P[64][72];      // 9 KB softmax weights

  // stage K chunk0 (chans 0-255)
  for (int u = 0; u < 8; ++u) {
    int row = 16 * w + 2 * u + (lane >> 5);
    int c = lane & 31;
    async16(&Kp[qkbase + (long)row * H + ((c ^ (row & 7)) * 8)],
            &Ks[(16 * w + 2 * u) * 256]);
  }
  asm volatile("" ::: "memory");     // pin K0 first in the vmcnt ledger
  bf16x8 qf[16];
  for (int t = 0; t < 16; ++t)
    qf[t] = *(const bf16x8*)&Qp[qkbase + (long)(16 * w + ln) * H + t * 32 + qd * 8];
  // stage V chunk0 (V^T rows 0-255)
  for (int u = 0; u < 8; ++u) {
    int rowb = 64 * w + 8 * u;
    async16(&Vt[vbase + (long)(rowb + (lane >> 3)) * 64 +
                (((lane & 7) ^ ((lane >> 3) & 7)) * 8)],
            &Vs[rowb * 64]);
  }
  asm volatile("s_waitcnt vmcnt(24)" ::: "memory");   // K0 landed (Q+V0 fly)
  __builtin_amdgcn_s_barrier();

  // QK chunk0: chans 0-255 (t = 0..7)
  f32x4 accs[4];
  for (int j = 0; j < 4; ++j) accs[j] = (f32x4){0.f, 0.f, 0.f, 0.f};
  for (int t = 0; t < 8; ++t)
    for (int j = 0; j < 4; ++j) {
      bf16x8 kf = *(const bf16x8*)&Ks[(16 * j + ln) * 256 + (((t * 4 + qd) ^ l7) * 8)];
      accs[j] = mfma16(qf[t], kf, accs[j]);
    }
  asm volatile("s_waitcnt lgkmcnt(0)" ::: "memory");
  __builtin_amdgcn_s_barrier();       // all waves done reading K0
  // stage K chunk1 (chans 256-511) into the same slab
  for (int u = 0; u < 8; ++u) {
    int row = 16 * w + 2 * u + (lane >> 5);
    int c = lane & 31;
    async16(&Kp[qkbase + (long)row * H + 256 + ((c ^ (row & 7)) * 8)],
            &Ks[(16 * w + 2 * u) * 256]);
  }
  asm volatile("s_waitcnt vmcnt(0)" ::: "memory");    // K1 (and V0) landed
  __builtin_amdgcn_s_barrier();
  // QK chunk1: chans 256-511 (t = 8..15)
  for (int t = 8; t < 16; ++t)
    for (int j = 0; j < 4; ++j) {
      bf16x8 kf = *(const bf16x8*)&Ks[(16 * j + ln) * 256 + ((((t - 8) * 4 + qd) ^ l7) * 8)];
      accs[j] = mfma16(qf[t], kf, accs[j]);
    }

  // register softmax, normalized weights into P (LDS)
  const float rscale = rsqrtf((float)H);
  for (int r = 0; r < 4; ++r) {
    float s[4];
    for (int j = 0; j < 4; ++j) s[j] = accs[j][r] * rscale;
    float mx = fmaxf(fmaxf(s[0], s[1]), fmaxf(s[2], s[3]));
    mx = fmaxf(mx, __shfl_xor(mx, 1));
    mx = fmaxf(mx, __shfl_xor(mx, 2));
    mx = fmaxf(mx, __shfl_xor(mx, 4));
    mx = fmaxf(mx, __shfl_xor(mx, 8));
    float e[4], sum = 0.f;
    for (int j = 0; j < 4; ++j) {
      e[j] = (float)(bf16_t)__expf(s[j] - mx);
      sum += e[j];
    }
    sum += __shfl_xor(sum, 1);
    sum += __shfl_xor(sum, 2);
    sum += __shfl_xor(sum, 4);
    sum += __shfl_xor(sum, 8);
    float rs = 1.f / sum;
    for (int j = 0; j < 4; ++j)
      P[16 * w + qd * 4 + r][16 * j + ln] = (bf16_t)(e[j] * rs);
  }
  asm volatile("s_waitcnt lgkmcnt(0)" ::: "memory");
  __builtin_amdgcn_s_barrier();   // P visible; Ks dead -> scratch; Vs = V0

  unsigned char* scratch = (unsigned char*)Ks;   // [64 rows][512 B]
  const int m = 16 * w + ln;
  const long orow = (long)b * S + h * 64;

#pragma unroll
  for (int half = 0; half < 2; ++half) {
    for (int nc = 0; nc < 2; ++nc) {
      f32x4 acco[8];
      for (int j = 0; j < 8; ++j) acco[j] = (f32x4){0.f, 0.f, 0.f, 0.f};
      for (int ks = 0; ks < 2; ++ks) {
        bf16x8 pf = *(const bf16x8*)&P[m][ks * 32 + qd * 8];
        for (int j = 0; j < 8; ++j) {
          int row = nc * 128 + 16 * j + ln;
          bf16x8 vf = *(const bf16x8*)&Vs[row * 64 + (((ks * 4 + qd) ^ l7) * 8)];
          acco[j] = mfma16(vf, pf, acco[j]);
        }
      }
      for (int j = 0; j < 8; ++j) {
        int c16 = nc * 16 + 2 * j + (qd >> 1);
        bf16x4 pk;
        for (int r = 0; r < 4; ++r) pk[r] = (bf16_t)acco[j][r];
        *(bf16x4*)(scratch + m * 512 + ((c16 ^ l7) * 16) + (qd & 1) * 8) = pk;
      }
    }
    asm volatile("s_waitcnt lgkmcnt(0)" ::: "memory");
    __builtin_amdgcn_s_barrier();     // Vs reads + scratch writes done
    if (half == 0) {
      // stage V chunk1 (V^T rows 256-511) while half0 stores run
      for (int u = 0; u < 8; ++u) {
        int rowb = 64 * w + 8 * u;
        async16(&Vt[vbase + (long)(256 + rowb + (lane >> 3)) * 64 +
                    (((lane & 7) ^ ((lane >> 3) & 7)) * 8)],
                &Vs[rowb * 64]);
      }
    }
    // store this half: contiguous 512 B runs per half-wave
    for (int k = 0; k < 8; ++k) {
      int row = 16 * w + 2 * k + (lane >> 5);
      int c = lane & 31;
      bf16x8 v = *(const bf16x8*)(scratch + row * 512 + ((c ^ (row & 7)) * 16));
      *(bf16x8*)&Att[(orow + row) * H + half * 256 + c * 8] = v;
    }
    if (half == 0) {
      asm volatile("s_waitcnt vmcnt(0)" ::: "memory");  // V1 landed
      __builtin_amdgcn_s_barrier();
    }
  }
}

extern "C" void kernel_launch(void* const* d_in, const int* in_sizes, int n_in,
                              void* d_out, int out_size, void* d_ws, size_t ws_size,
                              hipStream_t stream)
{
  const float* x  = (const float*)d_in[0];
  const float* Wq = (const float*)d_in[1]; const float* bq = (const float*)d_in[2];
  const float* Wk = (const float*)d_in[3]; const float* bk = (const float*)d_in[4];
  const float* Wv = (const float*)d_in[5]; const float* bv = (const float*)d_in[6];
  const float* Wo = (const float*)d_in[7]; const float* bo = (const float*)d_in[8];
  const int* perm = (const int*)d_in[9];

  const int S = in_sizes[9];                 // 4096
  const int H = in_sizes[2];                 // 512
  const int B = in_sizes[0] / (S * H);       // 8
  const int M = B * S;                       // 32768

  size_t bufB = (size_t)M * H * sizeof(bf16_t);          // 32 MB
  size_t wB   = 4 * (size_t)H * H * sizeof(bf16_t);
  size_t need = 256 + 4 * bufB + wB + 4 * H * 2 + (size_t)S * 4;
  if (ws_size < need) return;

  char* p = (char*)d_ws;  p += 256;
  bf16_t* Xp = (bf16_t*)p;  p += bufB;        // aliased as Att after QKV GEMM
  bf16_t* Qp = (bf16_t*)p;  p += bufB;
  bf16_t* Kp = (bf16_t*)p;  p += bufB;
  bf16_t* Vt = (bf16_t*)p;  p += bufB;        // V^T: [b][head][chan][tok]
  bf16_t* Wb = (bf16_t*)p;  p += wB;
  bf16_t* bb = (bf16_t*)p;  p += 4 * H * 2;
  int* invp  = (int*)p;
  bf16_t* Att = Xp;

  invperm_kernel<<<(S + 255) / 256, 256, 0, stream>>>(perm, invp, S);
  convert_x_kernel<<<(M * H) / 2048, 256, 0, stream>>>(x, Xp, perm, S, H);
  dim3 gw((H * H) / 2048 + 1, 1, 4);
  convert_w_kernel<<<gw, 256, 0, stream>>>(Wq, bq, Wk, bk, Wv, bv, Wo, bo,
                                           Wb, bb, H);

  dim3 g1(M / 256, H / 256, 3);
  gemm_qkv_kernel<<<g1, 512, 0, stream>>>(Xp, Wb, bb, Qp, Kp, Vt, S, H);

  dim3 g2(B * (S / 64));
  attn_kernel<<<g2, 256, 0, stream>>>(Qp, Kp, Vt, Att, S, H);

  dim3 g3(M / 256, H / 256, 1);
  gemm_o_kernel<<<g3, 512, 0, stream>>>(Att, Wb, bb, (float*)d_out, invp, S, H);
}